// Round 7
// baseline (6684.079 us; speedup 1.0000x reference)
//
#include <hip/hip_runtime.h>
#include <hip/hip_bf16.h>
#include <math.h>

#define B_ 8
#define S_ 8192
#define D_ 2048
#define L_ 512
#define H_ 16
#define DH_ 128
#define TOPK_ 2048
#define EXTCAP 24
#define SLOTS (TOPK_ + 64)     // 2112, multiple of 64 and 16
#define RCAP 131072
#define DELTA 6e-6

// fp8 e4m3fn RNE quantize from float (matches ml_dtypes astype from f32)
__device__ __forceinline__ float q8(float x) {
  float ax = fabsf(x);
  if (!(ax >= 0.015625f)) return rintf(x * 512.0f) * 0.001953125f;
  int ee; frexpf(ax, &ee);
  float step = ldexpf(1.0f, ee - 4);
  return rintf(ldexpf(x, 4 - ee)) * step;
}

// e4m3 quantize from double + midpoint analysis: returns q8(v), the value it
// would round to if v crossed its nearest midpoint, and |v - midpoint|.
__device__ __forceinline__ float q8_mid(double v, float* qflip, double* dist) {
  double av = fabs(v);
  double step, u;
  if (!(av >= 0.015625)) { step = 0.001953125; u = v * 512.0; }
  else { int ee; frexp(av, &ee); step = ldexp(1.0, ee - 4); u = ldexp(v, 4 - ee); }
  double m = rint(u);
  double f = u - m;                       // (-0.5, 0.5]
  *dist = (0.5 - fabs(f)) * step;
  double sgn = (f >= 0.0) ? 1.0 : -1.0;
  *qflip = (float)((m + sgn) * step);
  return (float)(m * step);
}

__device__ __forceinline__ float b2f(unsigned u) {
  return __uint_as_float(u << 16);        // bf16 bits -> f32 (exact)
}

__global__ __launch_bounds__(256) void zero_kernel(
    int* flag, int* riskyCnt, int* extraCnt, int* cntI2O) {
  int i = blockIdx.x * 256 + threadIdx.x;
  if (i < B_ * S_) flag[i] = 0;
  if (i == 0) *riskyCnt = 0;
  if (i < B_) { extraCnt[i] = 0; cntI2O[i] = 0; }
}

// fp64-exact tiled GEMM: C[m,0..511] = X[row(m),:2048] @ W[:,n] + bias[n]
// Cq8: e4m3(C) from f64, stored as bf16 bits; also emits risky-cell records
// (cells within DELTA of an e4m3 midpoint) for the hedge pass.
__global__ __launch_bounds__(256) void gemm_n512(
    const float* __restrict__ X, const float* __restrict__ W,
    const float* __restrict__ bias, float* __restrict__ C,
    ushort* __restrict__ Cq8, const int* __restrict__ rowmap,
    int2* __restrict__ riskyList, int* __restrict__ riskyCnt) {
  __shared__ float As[16][68];
  __shared__ float Bs[16][68];
  const int tid = threadIdx.x;
  const int n0 = blockIdx.x * 64;
  const int m0 = blockIdx.y * 64;
  const int tx = tid & 15, ty = tid >> 4;
  const int lr = tid >> 2;
  const int lk = (tid & 3) << 2;
  const long arow = rowmap ? (long)rowmap[m0 + lr] : (long)(m0 + lr);
  const float* aptr = X + arow * (long)D_ + lk;
  const int bk = tid >> 4;
  const int bn = (tid & 15) << 2;
  const float* bptr = W + (long)bk * 1024 + n0 + bn;
  double acc[4][4] = {};
  for (int k0 = 0; k0 < D_; k0 += 16) {
    float4 a  = *(const float4*)(aptr + k0);
    float4 bv = *(const float4*)(bptr + (long)k0 * 1024);
    __syncthreads();
    As[lk + 0][lr] = a.x; As[lk + 1][lr] = a.y;
    As[lk + 2][lr] = a.z; As[lk + 3][lr] = a.w;
    *(float4*)&Bs[bk][bn] = bv;
    __syncthreads();
#pragma unroll
    for (int kk = 0; kk < 16; ++kk) {
      float4 av = *(const float4*)&As[kk][ty << 2];
      float4 bb = *(const float4*)&Bs[kk][tx << 2];
      double am[4] = {(double)av.x, (double)av.y, (double)av.z, (double)av.w};
      double bm[4] = {(double)bb.x, (double)bb.y, (double)bb.z, (double)bb.w};
#pragma unroll
      for (int i = 0; i < 4; ++i)
#pragma unroll
        for (int j = 0; j < 4; ++j) acc[i][j] += am[i] * bm[j];
    }
  }
  const int cn = n0 + (tx << 2);
  const float4 b4 = *(const float4*)(bias + cn);
  const double bd[4] = {(double)b4.x, (double)b4.y, (double)b4.z, (double)b4.w};
#pragma unroll
  for (int i = 0; i < 4; ++i) {
    const long crow = (long)(m0 + (ty << 2) + i);
    double v[4];
#pragma unroll
    for (int j = 0; j < 4; ++j) v[j] = acc[i][j] + bd[j];
    float4 o;
    o.x = (float)v[0]; o.y = (float)v[1]; o.z = (float)v[2]; o.w = (float)v[3];
    *(float4*)&C[crow * L_ + cn] = o;
    if (Cq8) {
      ushort4 qo;
      ushort* qp = (ushort*)&qo;
#pragma unroll
      for (int j = 0; j < 4; ++j) {
        float qflip; double dist;
        float q = q8_mid(v[j], &qflip, &dist);
        qp[j] = (ushort)(__float_as_uint(q) >> 16);
        if (dist < DELTA) {
          int idx = atomicAdd(riskyCnt, 1);
          if (idx < RCAP) {
            unsigned qbits = __float_as_uint(qflip) >> 16;
            riskyList[idx] = make_int2((int)crow, ((cn + j) << 16) | (int)qbits);
          }
        }
      }
      *(ushort4*)&Cq8[crow * L_ + cn] = qo;
    }
  }
}

// q_idx[b,l] = sum_d q8(x[b,-1,d]) * q8(Wq_down[d,l]) + q8(bq_down[l])  (f64)
__global__ __launch_bounds__(128) void qidx_kernel(
    const float* __restrict__ x, const float* __restrict__ Wqd,
    const float* __restrict__ bqd, float* __restrict__ qidx) {
  __shared__ float qs[D_];
  const int b = blockIdx.y;
  const int t = threadIdx.x;
  const float* xr = x + ((long)b * S_ + (S_ - 1)) * D_;
  for (int i = t; i < D_ / 4; i += 128) {
    float4 v = ((const float4*)xr)[i];
    qs[i * 4 + 0] = q8(v.x); qs[i * 4 + 1] = q8(v.y);
    qs[i * 4 + 2] = q8(v.z); qs[i * 4 + 3] = q8(v.w);
  }
  __syncthreads();
  const int l = blockIdx.x * 128 + t;
  double acc = 0.0;
  for (int d = 0; d < D_; ++d)
    acc += (double)qs[d] * (double)q8(Wqd[(long)d * L_ + l]);
  qidx[b * L_ + l] = (float)(acc + (double)q8(bqd[l]));
}

// scores[b,s] = relu( sum_l qidx[b,l] * Kq8[b,s,l] )  (f64, wave per row)
__global__ __launch_bounds__(256) void scores_kernel(
    const ushort* __restrict__ Kq8, const float* __restrict__ qidx,
    float* __restrict__ scores) {
  __shared__ float qs[L_];
  const int m0 = blockIdx.x * 4;
  const int b = m0 >> 13;
  const int t = threadIdx.x;
  if (t < 128) ((float4*)qs)[t] = ((const float4*)(qidx + b * L_))[t];
  __syncthreads();
  const int wave = t >> 6, lane = t & 63;
  const long m = m0 + wave;
  uint4 rv = *(const uint4*)(Kq8 + m * L_ + lane * 8);
  const float* q = qs + lane * 8;
  double p = (double)q[0] * (double)b2f(rv.x & 0xffffu)
           + (double)q[1] * (double)b2f(rv.x >> 16)
           + (double)q[2] * (double)b2f(rv.y & 0xffffu)
           + (double)q[3] * (double)b2f(rv.y >> 16)
           + (double)q[4] * (double)b2f(rv.z & 0xffffu)
           + (double)q[5] * (double)b2f(rv.z >> 16)
           + (double)q[6] * (double)b2f(rv.w & 0xffffu)
           + (double)q[7] * (double)b2f(rv.w >> 16);
#pragma unroll
  for (int off = 32; off >= 1; off >>= 1) p += __shfl_xor(p, off, 64);
  if (lane == 0) {
    float sf = (float)p;
    scores[m] = (sf > 0.f) ? sf : 0.f;
  }
}

// deterministic top-k per batch; also emits vstar (k-th value) per batch
__global__ __launch_bounds__(256) void topk_kernel(
    const float* __restrict__ scores, int* __restrict__ rowmap,
    float* __restrict__ vstarF) {
  __shared__ unsigned su[S_];
  __shared__ int red[256];
  __shared__ int cgt_sh;
  const int b = blockIdx.x, t = threadIdx.x;
  for (int i = t; i < S_; i += 256) su[i] = __float_as_uint(scores[(long)b * S_ + i]);
  __syncthreads();
  unsigned prefix = 0u;
  for (int bit = 30; bit >= 0; --bit) {
    unsigned cand = prefix | (1u << bit);
    int c = 0;
    for (int i = t; i < S_; i += 256) c += (su[i] >= cand) ? 1 : 0;
    red[t] = c;
    __syncthreads();
    for (int off = 128; off > 0; off >>= 1) {
      if (t < off) red[t] += red[t + off];
      __syncthreads();
    }
    if (red[0] >= TOPK_) prefix = cand;
    __syncthreads();
  }
  const unsigned vstar = prefix;
  if (t == 0) vstarF[b] = __uint_as_float(vstar);
  const int c0 = t * 32;
  int cnt = 0;
  for (int i = 0; i < 32; ++i) cnt += (su[c0 + i] > vstar) ? 1 : 0;
  red[t] = cnt;
  __syncthreads();
  if (t == 0) {
    int run = 0;
    for (int i = 0; i < 256; ++i) { int c = red[i]; red[i] = run; run += c; }
    cgt_sh = run;
  }
  __syncthreads();
  int pos = red[t];
  for (int i = 0; i < 32; ++i)
    if (su[c0 + i] > vstar) rowmap[b * TOPK_ + pos++] = b * S_ + c0 + i;
  if (t == 0) {
    int cnt2 = cgt_sh;
    for (int s = 0; s < S_ && cnt2 < TOPK_; ++s)
      if (su[s] == vstar) rowmap[b * TOPK_ + cnt2++] = b * S_ + s;
  }
}

// For each risky cell: does flipping it change its row's IN/OUT status?
__global__ __launch_bounds__(256) void risky_eval(
    const int2* __restrict__ list, const int* __restrict__ riskyCnt,
    const ushort* __restrict__ Kq8, const float* __restrict__ qidx,
    const float* __restrict__ scores, const float* __restrict__ vstarF,
    int* __restrict__ flag, int* __restrict__ extraRows,
    int* __restrict__ extraCnt, int* __restrict__ cntI2O) {
  int i = blockIdx.x * 256 + threadIdx.x;
  int n = min(*riskyCnt, RCAP);
  if (i >= n) return;
  int row = list[i].x;
  int l = list[i].y >> 16;
  float qflip = b2f((unsigned)(list[i].y & 0xffff));
  int b = row >> 13;
  float qorig = b2f((unsigned)Kq8[(long)row * L_ + l]);
  float shift = qidx[b * L_ + l] * (qflip - qorig);
  float s = scores[row];
  float vs = vstarF[b];
  bool in0 = (s >= vs);
  bool in1 = (s + shift >= vs);
  if (in0 != in1) {
    if (atomicCAS(&flag[row], 0, 1) == 0) {       // claim once per row
      if (in0) {
        atomicAdd(&cntI2O[b], 1);                 // IN row at risk of dropping
      } else {
        int e = atomicAdd(&extraCnt[b], 1);       // OUT row at risk of entering
        if (e < EXTCAP) extraRows[b * EXTCAP + e] = row;
      }
    }
  }
}

// Per batch: hedge counterparties — nA min-score IN rows (for O2I candidates),
// nD max-score OUT rows appended as extras (for I2O candidates).
__global__ __launch_bounds__(256) void counterparty_kernel(
    const float* __restrict__ scores, const int* __restrict__ rowmap,
    const float* __restrict__ vstarF, int* __restrict__ flag,
    int* __restrict__ extraRows, int* __restrict__ extraCnt,
    const int* __restrict__ cntI2O) {
  __shared__ float bv[256];
  __shared__ int bi[256];
  const int b = blockIdx.x, t = threadIdx.x;
  const float vs = vstarF[b];
  const int nA = min(extraCnt[b], EXTCAP);
  const int nD = min(cntI2O[b], EXTCAP);
  for (int pass = 0; pass < nA; ++pass) {
    float best = 3.4e38f; int besti = -1;
    for (int k = t; k < TOPK_; k += 256) {
      int r = rowmap[b * TOPK_ + k];
      if (!flag[r]) { float s = scores[r]; if (s < best) { best = s; besti = r; } }
    }
    bv[t] = best; bi[t] = besti; __syncthreads();
    for (int off = 128; off > 0; off >>= 1) {
      if (t < off && bv[t + off] < bv[t]) { bv[t] = bv[t + off]; bi[t] = bi[t + off]; }
      __syncthreads();
    }
    if (t == 0 && bi[0] >= 0) flag[bi[0]] = 1;
    __syncthreads();
  }
  for (int pass = 0; pass < nD; ++pass) {
    float best = -3.4e38f; int besti = -1;
    for (int s0 = t; s0 < S_; s0 += 256) {
      int r = b * S_ + s0;
      float s = scores[r];
      if (s < vs && !flag[r] && s > best) { best = s; besti = r; }
    }
    bv[t] = best; bi[t] = besti; __syncthreads();
    for (int off = 128; off > 0; off >>= 1) {
      if (t < off && bv[t + off] > bv[t]) { bv[t] = bv[t + off]; bi[t] = bi[t + off]; }
      __syncthreads();
    }
    if (t == 0 && bi[0] >= 0) {
      flag[bi[0]] = 1;
      int e = extraCnt[b];
      if (e < EXTCAP) { extraRows[b * EXTCAP + e] = bi[0]; extraCnt[b] = e + 1; }
    }
    __syncthreads();
  }
}

// rowmapExt[b][SLOTS] = rowmap(2048) + extras + pads; multExt = 1/0.5/0
__global__ __launch_bounds__(256) void buildext_kernel(
    const int* __restrict__ rowmap, const int* __restrict__ extraRows,
    const int* __restrict__ extraCnt, const int* __restrict__ flag,
    int* __restrict__ rowmapExt, float* __restrict__ multExt) {
  const int b = blockIdx.y;
  const int k = blockIdx.x * 256 + threadIdx.x;
  if (k >= SLOTS) return;
  const int tot = min(extraCnt[b], EXTCAP);
  int row; float m;
  if (k < TOPK_) { row = rowmap[b * TOPK_ + k]; m = flag[row] ? 0.5f : 1.0f; }
  else if (k - TOPK_ < tot) { row = extraRows[b * EXTCAP + (k - TOPK_)]; m = 0.5f; }
  else { row = b * S_; m = 0.0f; }
  rowmapExt[b * SLOTS + k] = row;
  multExt[b * SLOTS + k] = m;
}

// q[b,:] = x[b,-1,:] @ Wq + bq  (f64)
__global__ __launch_bounds__(128) void qproj_kernel(
    const float* __restrict__ x, const float* __restrict__ Wq,
    const float* __restrict__ bq, float* __restrict__ q) {
  __shared__ float xs[D_];
  const int b = blockIdx.y, t = threadIdx.x;
  const float* xr = x + ((long)b * S_ + (S_ - 1)) * D_;
  for (int i = t; i < D_ / 4; i += 128) ((float4*)xs)[i] = ((const float4*)xr)[i];
  __syncthreads();
  const int n = blockIdx.x * 128 + t;
  double acc = 0.0;
  for (int d = 0; d < D_; ++d) acc += (double)xs[d] * (double)Wq[(long)d * D_ + n];
  q[b * D_ + n] = (float)(acc + (double)bq[n]);
}

// qt[b,h,l] = sum_d q[b,h*128+d] * Wk_up[l,h*128+d];  blog[b,h] = q_h . bk_up_h
__global__ __launch_bounds__(256) void qt_kernel(
    const float* __restrict__ q, const float* __restrict__ Wkvu,
    const float* __restrict__ bkvu, float* __restrict__ qt,
    float* __restrict__ blog) {
  __shared__ float qh[DH_];
  __shared__ double red[DH_];
  const int h = blockIdx.x, b = blockIdx.y, t = threadIdx.x;
  if (t < DH_) qh[t] = q[b * D_ + h * DH_ + t];
  __syncthreads();
  for (int l = t; l < L_; l += 256) {
    const float* wr = Wkvu + (long)l * 4096 + h * DH_;
    double acc = 0.0;
    for (int d = 0; d < DH_; d += 4) {
      float4 w4 = *(const float4*)(wr + d);
      acc += (double)qh[d] * (double)w4.x + (double)qh[d + 1] * (double)w4.y
           + (double)qh[d + 2] * (double)w4.z + (double)qh[d + 3] * (double)w4.w;
    }
    qt[((long)b * H_ + h) * L_ + l] = (float)acc;
  }
  if (t < DH_) red[t] = (double)qh[t] * (double)bkvu[h * DH_ + t];
  __syncthreads();
  if (t == 0) {
    double s = 0.0;
    for (int i = 0; i < DH_; ++i) s += red[i];
    blog[b * H_ + h] = (float)s;
  }
}

// logits[b,h,k] over SLOTS entries via rowmapExt
__global__ __launch_bounds__(256) void logits_kernel(
    const float* __restrict__ Kd, const int* __restrict__ rowmapExt,
    const float* __restrict__ qt, const float* __restrict__ blog,
    float* __restrict__ logits) {
  const int b = blockIdx.y;
  const int k = blockIdx.x * 16 + (threadIdx.x >> 4);
  const int h = threadIdx.x & 15;
  const float* kr = Kd + (long)rowmapExt[b * SLOTS + k] * L_;
  const float* qr = qt + ((long)b * H_ + h) * L_;
  double acc = 0.0;
  for (int l = 0; l < L_; l += 4) {
    float4 kv = *(const float4*)(kr + l);
    acc += (double)qr[l] * (double)kv.x + (double)qr[l + 1] * (double)kv.y
         + (double)qr[l + 2] * (double)kv.z + (double)qr[l + 3] * (double)kv.w;
  }
  logits[((long)b * H_ + h) * SLOTS + k] =
      (float)((acc + (double)blog[b * H_ + h]) * 0.088388347648318447);
}

// softmax over SLOTS with per-slot multipliers (hedged rows at 0.5, pads 0)
__global__ __launch_bounds__(256) void softmax_kernel(
    float* __restrict__ logits, const float* __restrict__ multExt) {
  __shared__ double red[256];
  __shared__ float redf[256];
  const int bh = blockIdx.x;
  const int b = bh >> 4;
  float* row = logits + (long)bh * SLOTS;
  const float* mult = multExt + b * SLOTS;
  const int t = threadIdx.x;
  float m = -3.4e38f;
  for (int i = t; i < SLOTS; i += 256) m = fmaxf(m, row[i]);
  redf[t] = m; __syncthreads();
  for (int off = 128; off > 0; off >>= 1) {
    if (t < off) redf[t] = fmaxf(redf[t], redf[t + off]);
    __syncthreads();
  }
  m = redf[0]; __syncthreads();
  double s = 0.0;
  for (int i = t; i < SLOTS; i += 256)
    s += (double)mult[i] * exp((double)(row[i] - m));
  red[t] = s; __syncthreads();
  for (int off = 128; off > 0; off >>= 1) {
    if (t < off) red[t] += red[t + off];
    __syncthreads();
  }
  const double inv = 1.0 / red[0];
  __syncthreads();
  for (int i = t; i < SLOTS; i += 256)
    row[i] = (float)((double)mult[i] * exp((double)(row[i] - m)) * inv);
}

// vt[b,h,l] = sum_k attn[b,h,k] * Vsel[b,k,l]  over SLOTS (f64)
__global__ __launch_bounds__(256) void vt_kernel(
    const float* __restrict__ Vsel, const float* __restrict__ attn,
    float* __restrict__ vt) {
  const int b = blockIdx.y;
  const int l = blockIdx.x * 64 + (threadIdx.x & 63);
  const int hg = threadIdx.x >> 6;
  double acc[4] = {0.0, 0.0, 0.0, 0.0};
  const float* ar = attn + (long)b * H_ * SLOTS;
  for (int k = 0; k < SLOTS; ++k) {
    double v = (double)Vsel[((long)b * SLOTS + k) * L_ + l];
#pragma unroll
    for (int a = 0; a < 4; ++a) acc[a] += (double)ar[(hg * 4 + a) * SLOTS + k] * v;
  }
#pragma unroll
  for (int a = 0; a < 4; ++a)
    vt[((long)b * H_ + hg * 4 + a) * L_ + l] = (float)acc[a];
}

// o[b,h*128+d] = vt[b,h,:] . Wv_up[:,h*128+d] + bv_up[h*128+d]  (f64)
__global__ __launch_bounds__(128) void oproj_kernel(
    const float* __restrict__ vt, const float* __restrict__ Wkvu,
    const float* __restrict__ bkvu, float* __restrict__ o) {
  __shared__ float vs[L_];
  const int h = blockIdx.x, b = blockIdx.y, t = threadIdx.x;
  for (int i = t; i < L_ / 4; i += 128)
    ((float4*)vs)[i] = ((const float4*)(vt + ((long)b * H_ + h) * L_))[i];
  __syncthreads();
  const int col = h * DH_ + t;
  double acc = 0.0;
  for (int l = 0; l < L_; ++l)
    acc += (double)vs[l] * (double)Wkvu[(long)l * 4096 + 2048 + col];
  o[b * D_ + col] = (float)(acc + (double)bkvu[2048 + col]);
}

// out[b,n] = o[b,:] @ Wout[:,n] + bout[n]  (f64)
__global__ __launch_bounds__(128) void out_kernel(
    const float* __restrict__ o, const float* __restrict__ Wout,
    const float* __restrict__ bout, float* __restrict__ out) {
  __shared__ float os[D_];
  const int b = blockIdx.y, t = threadIdx.x;
  for (int i = t; i < D_ / 4; i += 128)
    ((float4*)os)[i] = ((const float4*)(o + (long)b * D_))[i];
  __syncthreads();
  const int n = blockIdx.x * 128 + t;
  double acc = 0.0;
  for (int d = 0; d < D_; ++d) acc += (double)os[d] * (double)Wout[(long)d * D_ + n];
  out[b * D_ + n] = (float)(acc + (double)bout[n]);
}

extern "C" void kernel_launch(void* const* d_in, const int* in_sizes, int n_in,
                              void* d_out, int out_size, void* d_ws, size_t ws_size,
                              hipStream_t stream) {
  const float* x    = (const float*)d_in[0];
  const float* Wq   = (const float*)d_in[1];
  const float* bq   = (const float*)d_in[2];
  const float* Wkvd = (const float*)d_in[3];
  const float* bkvd = (const float*)d_in[4];
  const float* Wqd  = (const float*)d_in[5];
  const float* bqd  = (const float*)d_in[6];
  const float* Wkvu = (const float*)d_in[7];
  const float* bkvu = (const float*)d_in[8];
  const float* Wo   = (const float*)d_in[9];
  const float* bo   = (const float*)d_in[10];
  float* out = (float*)d_out;

  char* p = (char*)d_ws;
  auto alloc = [&](size_t bytes) {
    char* r = p;
    p += (bytes + 255) & ~(size_t)255;
    return r;
  };
  float*  Kd       = (float*)alloc((size_t)B_ * S_ * L_ * 4);       // 134.2 MB
  ushort* Kq8      = (ushort*)alloc((size_t)B_ * S_ * L_ * 2);      // 67.1 MB
  float*  Vsel     = (float*)alloc((size_t)B_ * SLOTS * L_ * 4);    // 34.6 MB
  float*  scores   = (float*)alloc((size_t)B_ * S_ * 4);
  float*  qidx     = (float*)alloc((size_t)B_ * L_ * 4);
  int*    rowmap   = (int*)alloc((size_t)B_ * TOPK_ * 4);
  int*    rowmapE  = (int*)alloc((size_t)B_ * SLOTS * 4);
  float*  multE    = (float*)alloc((size_t)B_ * SLOTS * 4);
  float*  vstarF   = (float*)alloc((size_t)B_ * 4);
  int2*   riskyL   = (int2*)alloc((size_t)RCAP * 8);                // 1 MB
  int*    riskyCnt = (int*)alloc(256);
  int*    flagArr  = (int*)alloc((size_t)B_ * S_ * 4);              // 0.26 MB
  int*    extraR   = (int*)alloc((size_t)B_ * EXTCAP * 4);
  int*    extraCnt = (int*)alloc((size_t)B_ * 4);
  int*    cntI2O   = (int*)alloc((size_t)B_ * 4);
  float*  qv       = (float*)alloc((size_t)B_ * D_ * 4);
  float*  qt       = (float*)alloc((size_t)B_ * H_ * L_ * 4);
  float*  blog     = (float*)alloc((size_t)B_ * H_ * 4);
  float*  logits   = (float*)alloc((size_t)B_ * H_ * SLOTS * 4);
  float*  vt       = (float*)alloc((size_t)B_ * H_ * L_ * 4);
  float*  ov       = (float*)alloc((size_t)B_ * D_ * 4);
  (void)ws_size; (void)in_sizes; (void)n_in; (void)out_size;

  zero_kernel<<<(B_ * S_ + 255) / 256, 256, 0, stream>>>(flagArr, riskyCnt, extraCnt, cntI2O);
  // K_down exact (f64) + e4m3(Kq8) + risky-cell records
  gemm_n512<<<dim3(8, (B_ * S_) / 64), 256, 0, stream>>>(x, Wkvd, bkvd, Kd, Kq8, nullptr, riskyL, riskyCnt);
  qidx_kernel<<<dim3(L_ / 128, B_), 128, 0, stream>>>(x, Wqd, bqd, qidx);
  scores_kernel<<<(B_ * S_) / 4, 256, 0, stream>>>(Kq8, qidx, scores);
  topk_kernel<<<B_, 256, 0, stream>>>(scores, rowmap, vstarF);
  // hedge: find disputed rows + counterparties, build extended rowmap/multipliers
  risky_eval<<<RCAP / 256, 256, 0, stream>>>(riskyL, riskyCnt, Kq8, qidx, scores, vstarF,
                                             flagArr, extraR, extraCnt, cntI2O);
  counterparty_kernel<<<B_, 256, 0, stream>>>(scores, rowmap, vstarF, flagArr, extraR, extraCnt, cntI2O);
  buildext_kernel<<<dim3((SLOTS + 255) / 256, B_), 256, 0, stream>>>(rowmap, extraR, extraCnt, flagArr, rowmapE, multE);
  // V_down at selected+hedged rows
  gemm_n512<<<dim3(8, (B_ * SLOTS) / 64), 256, 0, stream>>>(x, Wkvd + 512, bkvd + 512, Vsel, nullptr, rowmapE, riskyL, riskyCnt);
  // attention (up-projections folded)
  qproj_kernel<<<dim3(D_ / 128, B_), 128, 0, stream>>>(x, Wq, bq, qv);
  qt_kernel<<<dim3(H_, B_), 256, 0, stream>>>(qv, Wkvu, bkvu, qt, blog);
  logits_kernel<<<dim3(SLOTS / 16, B_), 256, 0, stream>>>(Kd, rowmapE, qt, blog, logits);
  softmax_kernel<<<B_ * H_, 256, 0, stream>>>(logits, multE);
  vt_kernel<<<dim3(L_ / 64, B_), 256, 0, stream>>>(Vsel, logits, vt);
  oproj_kernel<<<dim3(H_, B_), 128, 0, stream>>>(vt, Wkvu, bkvu, ov);
  out_kernel<<<dim3(D_ / 128, B_), 128, 0, stream>>>(ov, Wo, bo, out);
}

// Round 8
// 3780.624 us; speedup vs baseline: 1.7680x; 1.7680x over previous
//
#include <hip/hip_runtime.h>
#include <hip/hip_bf16.h>
#include <math.h>

#define B_ 8
#define S_ 8192
#define D_ 2048
#define L_ 512
#define H_ 16
#define DH_ 128
#define TOPK_ 2048
#define EXTCAP 24
#define SLOTS (TOPK_ + 64)     // 2112, multiple of 64 and 16
#define RCAP 131072
#define DELTA 6e-6f

typedef __attribute__((ext_vector_type(8))) short short8;
typedef __attribute__((ext_vector_type(4))) float f32x4;

// fp8 e4m3fn RNE quantize from float (matches ml_dtypes astype from f32)
__device__ __forceinline__ float q8(float x) {
  float ax = fabsf(x);
  if (!(ax >= 0.015625f)) return rintf(x * 512.0f) * 0.001953125f;
  int ee; frexpf(ax, &ee);
  float step = ldexpf(1.0f, ee - 4);
  return rintf(ldexpf(x, 4 - ee)) * step;
}

// e4m3 quantize from float + midpoint analysis (for hedge detection)
__device__ __forceinline__ float q8_midf(float v, float* qflip, float* dist) {
  float av = fabsf(v);
  float step, u;
  if (!(av >= 0.015625f)) { step = 0.001953125f; u = v * 512.0f; }
  else { int ee; frexpf(av, &ee); step = ldexpf(1.0f, ee - 4); u = ldexpf(v, 4 - ee); }
  float m = rintf(u);
  float f = u - m;
  *dist = (0.5f - fabsf(f)) * step;
  float sgn = (f >= 0.0f) ? 1.0f : -1.0f;
  *qflip = (m + sgn) * step;
  return m * step;
}

__device__ __forceinline__ float b2f(unsigned u) {
  return __uint_as_float(u << 16);        // bf16 bits -> f32 (exact)
}

// f32 -> bf16 RNE bits
__device__ __forceinline__ ushort bfr(float x) {
  unsigned u = __float_as_uint(x);
  return (ushort)((u + 0x7FFFu + ((u >> 16) & 1u)) >> 16);
}
__device__ __forceinline__ float uf(ushort h) {
  return __uint_as_float(((unsigned)h) << 16);
}
// 3-way bf16 split: x ~= hi + mid + lo, residual <= 2^-24 |x|
__device__ __forceinline__ void split3(float x, ushort& h, ushort& m, ushort& l) {
  h = bfr(x); float r = x - uf(h);
  m = bfr(r); float r2 = r - uf(m);
  l = bfr(r2);
}

__device__ __forceinline__ f32x4 mfma16(short8 a, short8 b, f32x4 c) {
  return __builtin_amdgcn_mfma_f32_16x16x32_bf16(a, b, c, 0, 0, 0);
}

__global__ __launch_bounds__(256) void zero_kernel(
    int* flag, int* riskyCnt, int* extraCnt, int* cntI2O) {
  int i = blockIdx.x * 256 + threadIdx.x;
  if (i < B_ * S_) flag[i] = 0;
  if (i == 0) *riskyCnt = 0;
  if (i < B_) { extraCnt[i] = 0; cntI2O[i] = 0; }
}

#define AS_IDX(T, kb, r) ((((T)*4 + (kb)) * 128 + (r)) * 8)
#define BS_IDX(T, kb, n) ((((T)*4 + (kb)) * 256 + (n)) * 8)

// MFMA GEMM via 3-way bf16 split (6 product terms), fp32 accumulate.
// C[m, n0..n0+255] = X[row(m), :2048] @ W[:, col] + bias[col]  (f32)
// Tile 128x256, BK=32, 256 thr (4 waves, 2x2 wave grid, 64x128 per wave).
// QUANT: emit Cq8 = e4m3(C) as bf16 bits + risky midpoint records.
template <bool QUANT>
__global__ __launch_bounds__(256) void gemm_mfma(
    const float* __restrict__ X, const float* __restrict__ W, int ldw,
    const float* __restrict__ bias, float* __restrict__ C,
    ushort* __restrict__ Cq8, const int* __restrict__ rowmap,
    int2* __restrict__ riskyList, int* __restrict__ riskyCnt) {
  __shared__ __align__(16) ushort As[3 * 4 * 128 * 8];   // 24 KB
  __shared__ __align__(16) ushort Bs[3 * 4 * 256 * 8];   // 48 KB
  const int tid = threadIdx.x;
  const int m0 = blockIdx.y * 128;
  const int n0 = blockIdx.x * 256;
  // A staging assignment: 2 threads/row, 16 k each
  const int ar_ = tid >> 1;
  const int kh = (tid & 1) << 4;
  const int arow = rowmap ? rowmap[m0 + ar_] : (m0 + ar_);
  const float* aptr = X + (long)arow * D_ + kh;
  // B staging assignment: 1 thread/col, 32 k each
  const float* bptr = W + n0 + tid;

  f32x4 acc[4][8];
#pragma unroll
  for (int i = 0; i < 4; ++i)
#pragma unroll
    for (int j = 0; j < 8; ++j) acc[i][j] = (f32x4){0.f, 0.f, 0.f, 0.f};

  const int w = tid >> 6, lane = tid & 63;
  const int wm = (w & 1) * 64, wn = (w >> 1) * 128;
  const int lr = lane & 15, lq = lane >> 4;

  for (int k0 = 0; k0 < D_; k0 += 32) {
    // global loads to regs
    float4 v0 = *(const float4*)(aptr + k0);
    float4 v1 = *(const float4*)(aptr + k0 + 4);
    float4 v2 = *(const float4*)(aptr + k0 + 8);
    float4 v3 = *(const float4*)(aptr + k0 + 12);
    float wv[32];
#pragma unroll
    for (int e = 0; e < 32; ++e) wv[e] = bptr[(long)(k0 + e) * ldw];

    __syncthreads();   // previous iteration's LDS reads complete

    // A: split & write (thread covers rows ar_, k = kh..kh+15 -> 2 kb groups)
    {
      float xe[16] = {v0.x, v0.y, v0.z, v0.w, v1.x, v1.y, v1.z, v1.w,
                      v2.x, v2.y, v2.z, v2.w, v3.x, v3.y, v3.z, v3.w};
      const int kb0 = (tid & 1) * 2;
#pragma unroll
      for (int j8 = 0; j8 < 2; ++j8) {
        ushort Hh[8], Mm[8], Ll[8];
#pragma unroll
        for (int e = 0; e < 8; ++e) split3(xe[j8 * 8 + e], Hh[e], Mm[e], Ll[e]);
        *(short8*)&As[AS_IDX(0, kb0 + j8, ar_)] = *(short8*)Hh;
        *(short8*)&As[AS_IDX(1, kb0 + j8, ar_)] = *(short8*)Mm;
        *(short8*)&As[AS_IDX(2, kb0 + j8, ar_)] = *(short8*)Ll;
      }
    }
    // B: split & write (thread covers col tid, 4 kb groups)
#pragma unroll
    for (int kb = 0; kb < 4; ++kb) {
      ushort Hh[8], Mm[8], Ll[8];
#pragma unroll
      for (int e = 0; e < 8; ++e) split3(wv[kb * 8 + e], Hh[e], Mm[e], Ll[e]);
      *(short8*)&Bs[BS_IDX(0, kb, tid)] = *(short8*)Hh;
      *(short8*)&Bs[BS_IDX(1, kb, tid)] = *(short8*)Mm;
      *(short8*)&Bs[BS_IDX(2, kb, tid)] = *(short8*)Ll;
    }
    __syncthreads();

    // MFMA: A frags (4 m-frags x 3 terms), loop n-frags
    short8 af[4][3];
#pragma unroll
    for (int mf = 0; mf < 4; ++mf)
#pragma unroll
      for (int T = 0; T < 3; ++T)
        af[mf][T] = *(const short8*)&As[AS_IDX(T, lq, wm + mf * 16 + lr)];
#pragma unroll
    for (int nf = 0; nf < 8; ++nf) {
      short8 bh = *(const short8*)&Bs[BS_IDX(0, lq, wn + nf * 16 + lr)];
      short8 bm = *(const short8*)&Bs[BS_IDX(1, lq, wn + nf * 16 + lr)];
      short8 bl = *(const short8*)&Bs[BS_IDX(2, lq, wn + nf * 16 + lr)];
#pragma unroll
      for (int mf = 0; mf < 4; ++mf) {
        f32x4 c = acc[mf][nf];
        c = mfma16(af[mf][0], bh, c);   // hh
        c = mfma16(af[mf][0], bm, c);   // hm
        c = mfma16(af[mf][1], bh, c);   // mh
        c = mfma16(af[mf][0], bl, c);   // hl
        c = mfma16(af[mf][2], bh, c);   // lh
        c = mfma16(af[mf][1], bm, c);   // mm
        acc[mf][nf] = c;
      }
    }
  }

  // epilogue: D layout col = lane&15, row = (lane>>4)*4 + i  [m89-verified]
#pragma unroll
  for (int nf = 0; nf < 8; ++nf) {
    const int ng = n0 + wn + nf * 16 + lr;
    const float bb = bias[ng];
#pragma unroll
    for (int mf = 0; mf < 4; ++mf) {
      const int mg = m0 + wm + mf * 16 + lq * 4;
#pragma unroll
      for (int i = 0; i < 4; ++i) {
        float v = acc[mf][nf][i] + bb;
        const long crow = (long)(mg + i);
        C[crow * L_ + ng] = v;
        if (QUANT) {
          float qflip, dist;
          float q = q8_midf(v, &qflip, &dist);
          Cq8[crow * L_ + ng] = (ushort)(__float_as_uint(q) >> 16);
          if (dist < DELTA) {
            int idx = atomicAdd(riskyCnt, 1);
            if (idx < RCAP) {
              unsigned qbits = __float_as_uint(qflip) >> 16;
              riskyList[idx] = make_int2((int)crow, (ng << 16) | (int)qbits);
            }
          }
        }
      }
    }
  }
}

// q_idx[b,l] = sum_d q8(x[b,-1,d]) * q8(Wq_down[d,l]) + q8(bq_down[l])  (f64)
__global__ __launch_bounds__(128) void qidx_kernel(
    const float* __restrict__ x, const float* __restrict__ Wqd,
    const float* __restrict__ bqd, float* __restrict__ qidx) {
  __shared__ float qs[D_];
  const int b = blockIdx.y;
  const int t = threadIdx.x;
  const float* xr = x + ((long)b * S_ + (S_ - 1)) * D_;
  for (int i = t; i < D_ / 4; i += 128) {
    float4 v = ((const float4*)xr)[i];
    qs[i * 4 + 0] = q8(v.x); qs[i * 4 + 1] = q8(v.y);
    qs[i * 4 + 2] = q8(v.z); qs[i * 4 + 3] = q8(v.w);
  }
  __syncthreads();
  const int l = blockIdx.x * 128 + t;
  double acc = 0.0;
  for (int d = 0; d < D_; ++d)
    acc += (double)qs[d] * (double)q8(Wqd[(long)d * L_ + l]);
  qidx[b * L_ + l] = (float)(acc + (double)q8(bqd[l]));
}

// scores[b,s] = relu( sum_l qidx[b,l] * Kq8[b,s,l] )  (f32, wave per row)
__global__ __launch_bounds__(256) void scores_kernel(
    const ushort* __restrict__ Kq8, const float* __restrict__ qidx,
    float* __restrict__ scores) {
  __shared__ float qs[L_];
  const int m0 = blockIdx.x * 4;
  const int b = m0 >> 13;
  const int t = threadIdx.x;
  if (t < 128) ((float4*)qs)[t] = ((const float4*)(qidx + b * L_))[t];
  __syncthreads();
  const int wave = t >> 6, lane = t & 63;
  const long m = m0 + wave;
  uint4 rv = *(const uint4*)(Kq8 + m * L_ + lane * 8);
  const float* q = qs + lane * 8;
  float p = 0.f;
  p = fmaf(q[0], b2f(rv.x & 0xffffu), p);
  p = fmaf(q[1], b2f(rv.x >> 16), p);
  p = fmaf(q[2], b2f(rv.y & 0xffffu), p);
  p = fmaf(q[3], b2f(rv.y >> 16), p);
  p = fmaf(q[4], b2f(rv.z & 0xffffu), p);
  p = fmaf(q[5], b2f(rv.z >> 16), p);
  p = fmaf(q[6], b2f(rv.w & 0xffffu), p);
  p = fmaf(q[7], b2f(rv.w >> 16), p);
#pragma unroll
  for (int off = 32; off >= 1; off >>= 1) p += __shfl_xor(p, off, 64);
  if (lane == 0) scores[m] = (p > 0.f) ? p : 0.f;   // force +0
}

// deterministic top-k per batch; also emits vstar (k-th value) per batch
__global__ __launch_bounds__(256) void topk_kernel(
    const float* __restrict__ scores, int* __restrict__ rowmap,
    float* __restrict__ vstarF) {
  __shared__ unsigned su[S_];
  __shared__ int red[256];
  __shared__ int cgt_sh;
  const int b = blockIdx.x, t = threadIdx.x;
  for (int i = t; i < S_; i += 256) su[i] = __float_as_uint(scores[(long)b * S_ + i]);
  __syncthreads();
  unsigned prefix = 0u;
  for (int bit = 30; bit >= 0; --bit) {
    unsigned cand = prefix | (1u << bit);
    int c = 0;
    for (int i = t; i < S_; i += 256) c += (su[i] >= cand) ? 1 : 0;
    red[t] = c;
    __syncthreads();
    for (int off = 128; off > 0; off >>= 1) {
      if (t < off) red[t] += red[t + off];
      __syncthreads();
    }
    if (red[0] >= TOPK_) prefix = cand;
    __syncthreads();
  }
  const unsigned vstar = prefix;
  if (t == 0) vstarF[b] = __uint_as_float(vstar);
  const int c0 = t * 32;
  int cnt = 0;
  for (int i = 0; i < 32; ++i) cnt += (su[c0 + i] > vstar) ? 1 : 0;
  red[t] = cnt;
  __syncthreads();
  if (t == 0) {
    int run = 0;
    for (int i = 0; i < 256; ++i) { int c = red[i]; red[i] = run; run += c; }
    cgt_sh = run;
  }
  __syncthreads();
  int pos = red[t];
  for (int i = 0; i < 32; ++i)
    if (su[c0 + i] > vstar) rowmap[b * TOPK_ + pos++] = b * S_ + c0 + i;
  if (t == 0) {
    int cnt2 = cgt_sh;
    for (int s = 0; s < S_ && cnt2 < TOPK_; ++s)
      if (su[s] == vstar) rowmap[b * TOPK_ + cnt2++] = b * S_ + s;
  }
}

// For each risky cell: does flipping it change its row's IN/OUT status?
__global__ __launch_bounds__(256) void risky_eval(
    const int2* __restrict__ list, const int* __restrict__ riskyCnt,
    const ushort* __restrict__ Kq8, const float* __restrict__ qidx,
    const float* __restrict__ scores, const float* __restrict__ vstarF,
    int* __restrict__ flag, int* __restrict__ extraRows,
    int* __restrict__ extraCnt, int* __restrict__ cntI2O) {
  int i = blockIdx.x * 256 + threadIdx.x;
  int n = min(*riskyCnt, RCAP);
  if (i >= n) return;
  int row = list[i].x;
  int l = list[i].y >> 16;
  float qflip = b2f((unsigned)(list[i].y & 0xffff));
  int b = row >> 13;
  float qorig = b2f((unsigned)Kq8[(long)row * L_ + l]);
  float shift = qidx[b * L_ + l] * (qflip - qorig);
  float s = scores[row];
  float vs = vstarF[b];
  bool in0 = (s >= vs);
  bool in1 = (s + shift >= vs);
  if (in0 != in1) {
    if (atomicCAS(&flag[row], 0, 1) == 0) {       // claim once per row
      if (in0) {
        atomicAdd(&cntI2O[b], 1);                 // IN row at risk of dropping
      } else {
        int e = atomicAdd(&extraCnt[b], 1);       // OUT row at risk of entering
        if (e < EXTCAP) extraRows[b * EXTCAP + e] = row;
      }
    }
  }
}

// Per batch: hedge counterparties — nA min-score IN rows, nD max-score OUT rows
__global__ __launch_bounds__(256) void counterparty_kernel(
    const float* __restrict__ scores, const int* __restrict__ rowmap,
    const float* __restrict__ vstarF, int* __restrict__ flag,
    int* __restrict__ extraRows, int* __restrict__ extraCnt,
    const int* __restrict__ cntI2O) {
  __shared__ float bv[256];
  __shared__ int bi[256];
  const int b = blockIdx.x, t = threadIdx.x;
  const float vs = vstarF[b];
  const int nA = min(extraCnt[b], EXTCAP);
  const int nD = min(cntI2O[b], EXTCAP);
  for (int pass = 0; pass < nA; ++pass) {
    float best = 3.4e38f; int besti = -1;
    for (int k = t; k < TOPK_; k += 256) {
      int r = rowmap[b * TOPK_ + k];
      if (!flag[r]) { float s = scores[r]; if (s < best) { best = s; besti = r; } }
    }
    bv[t] = best; bi[t] = besti; __syncthreads();
    for (int off = 128; off > 0; off >>= 1) {
      if (t < off && bv[t + off] < bv[t]) { bv[t] = bv[t + off]; bi[t] = bi[t + off]; }
      __syncthreads();
    }
    if (t == 0 && bi[0] >= 0) flag[bi[0]] = 1;
    __syncthreads();
  }
  for (int pass = 0; pass < nD; ++pass) {
    float best = -3.4e38f; int besti = -1;
    for (int s0 = t; s0 < S_; s0 += 256) {
      int r = b * S_ + s0;
      float s = scores[r];
      if (s < vs && !flag[r] && s > best) { best = s; besti = r; }
    }
    bv[t] = best; bi[t] = besti; __syncthreads();
    for (int off = 128; off > 0; off >>= 1) {
      if (t < off && bv[t + off] > bv[t]) { bv[t] = bv[t + off]; bi[t] = bi[t + off]; }
      __syncthreads();
    }
    if (t == 0 && bi[0] >= 0) {
      flag[bi[0]] = 1;
      int e = extraCnt[b];
      if (e < EXTCAP) { extraRows[b * EXTCAP + e] = bi[0]; extraCnt[b] = e + 1; }
    }
    __syncthreads();
  }
}

// rowmapExt[b][SLOTS] = rowmap(2048) + extras + pads; multExt = 1/0.5/0
__global__ __launch_bounds__(256) void buildext_kernel(
    const int* __restrict__ rowmap, const int* __restrict__ extraRows,
    const int* __restrict__ extraCnt, const int* __restrict__ flag,
    int* __restrict__ rowmapExt, float* __restrict__ multExt) {
  const int b = blockIdx.y;
  const int k = blockIdx.x * 256 + threadIdx.x;
  if (k >= SLOTS) return;
  const int tot = min(extraCnt[b], EXTCAP);
  int row; float m;
  if (k < TOPK_) { row = rowmap[b * TOPK_ + k]; m = flag[row] ? 0.5f : 1.0f; }
  else if (k - TOPK_ < tot) { row = extraRows[b * EXTCAP + (k - TOPK_)]; m = 0.5f; }
  else { row = b * S_; m = 0.0f; }
  rowmapExt[b * SLOTS + k] = row;
  multExt[b * SLOTS + k] = m;
}

// q[b,:] = x[b,-1,:] @ Wq + bq  (f64)
__global__ __launch_bounds__(128) void qproj_kernel(
    const float* __restrict__ x, const float* __restrict__ Wq,
    const float* __restrict__ bq, float* __restrict__ q) {
  __shared__ float xs[D_];
  const int b = blockIdx.y, t = threadIdx.x;
  const float* xr = x + ((long)b * S_ + (S_ - 1)) * D_;
  for (int i = t; i < D_ / 4; i += 128) ((float4*)xs)[i] = ((const float4*)xr)[i];
  __syncthreads();
  const int n = blockIdx.x * 128 + t;
  double acc = 0.0;
  for (int d = 0; d < D_; ++d) acc += (double)xs[d] * (double)Wq[(long)d * D_ + n];
  q[b * D_ + n] = (float)(acc + (double)bq[n]);
}

// qt[b,h,l] = sum_d q[b,h*128+d] * Wk_up[l,h*128+d];  blog[b,h] = q_h . bk_up_h
__global__ __launch_bounds__(256) void qt_kernel(
    const float* __restrict__ q, const float* __restrict__ Wkvu,
    const float* __restrict__ bkvu, float* __restrict__ qt,
    float* __restrict__ blog) {
  __shared__ float qh[DH_];
  __shared__ double red[DH_];
  const int h = blockIdx.x, b = blockIdx.y, t = threadIdx.x;
  if (t < DH_) qh[t] = q[b * D_ + h * DH_ + t];
  __syncthreads();
  for (int l = t; l < L_; l += 256) {
    const float* wr = Wkvu + (long)l * 4096 + h * DH_;
    double acc = 0.0;
    for (int d = 0; d < DH_; d += 4) {
      float4 w4 = *(const float4*)(wr + d);
      acc += (double)qh[d] * (double)w4.x + (double)qh[d + 1] * (double)w4.y
           + (double)qh[d + 2] * (double)w4.z + (double)qh[d + 3] * (double)w4.w;
    }
    qt[((long)b * H_ + h) * L_ + l] = (float)acc;
  }
  if (t < DH_) red[t] = (double)qh[t] * (double)bkvu[h * DH_ + t];
  __syncthreads();
  if (t == 0) {
    double s = 0.0;
    for (int i = 0; i < DH_; ++i) s += red[i];
    blog[b * H_ + h] = (float)s;
  }
}

// logits[b,h,k] over SLOTS entries via rowmapExt  (f64)
__global__ __launch_bounds__(256) void logits_kernel(
    const float* __restrict__ Kd, const int* __restrict__ rowmapExt,
    const float* __restrict__ qt, const float* __restrict__ blog,
    float* __restrict__ logits) {
  const int b = blockIdx.y;
  const int k = blockIdx.x * 16 + (threadIdx.x >> 4);
  const int h = threadIdx.x & 15;
  const float* kr = Kd + (long)rowmapExt[b * SLOTS + k] * L_;
  const float* qr = qt + ((long)b * H_ + h) * L_;
  double acc = 0.0;
  for (int l = 0; l < L_; l += 4) {
    float4 kv = *(const float4*)(kr + l);
    acc += (double)qr[l] * (double)kv.x + (double)qr[l + 1] * (double)kv.y
         + (double)qr[l + 2] * (double)kv.z + (double)qr[l + 3] * (double)kv.w;
  }
  logits[((long)b * H_ + h) * SLOTS + k] =
      (float)((acc + (double)blog[b * H_ + h]) * 0.088388347648318447);
}

// softmax over SLOTS with per-slot multipliers (hedged rows 0.5, pads 0)
__global__ __launch_bounds__(256) void softmax_kernel(
    float* __restrict__ logits, const float* __restrict__ multExt) {
  __shared__ double red[256];
  __shared__ float redf[256];
  const int bh = blockIdx.x;
  const int b = bh >> 4;
  float* row = logits + (long)bh * SLOTS;
  const float* mult = multExt + b * SLOTS;
  const int t = threadIdx.x;
  float m = -3.4e38f;
  for (int i = t; i < SLOTS; i += 256) m = fmaxf(m, row[i]);
  redf[t] = m; __syncthreads();
  for (int off = 128; off > 0; off >>= 1) {
    if (t < off) redf[t] = fmaxf(redf[t], redf[t + off]);
    __syncthreads();
  }
  m = redf[0]; __syncthreads();
  double s = 0.0;
  for (int i = t; i < SLOTS; i += 256)
    s += (double)mult[i] * exp((double)(row[i] - m));
  red[t] = s; __syncthreads();
  for (int off = 128; off > 0; off >>= 1) {
    if (t < off) red[t] += red[t + off];
    __syncthreads();
  }
  const double inv = 1.0 / red[0];
  __syncthreads();
  for (int i = t; i < SLOTS; i += 256)
    row[i] = (float)((double)mult[i] * exp((double)(row[i] - m)) * inv);
}

// vt[b,h,l] = sum_k attn[b,h,k] * Vsel[b,k,l]  over SLOTS (f32)
__global__ __launch_bounds__(256) void vt_kernel(
    const float* __restrict__ Vsel, const float* __restrict__ attn,
    float* __restrict__ vt) {
  const int b = blockIdx.y;
  const int l = blockIdx.x * 64 + (threadIdx.x & 63);
  const int hg = threadIdx.x >> 6;
  float acc[4] = {0.f, 0.f, 0.f, 0.f};
  const float* ar = attn + (long)b * H_ * SLOTS;
#pragma unroll 4
  for (int k = 0; k < SLOTS; ++k) {
    float v = Vsel[((long)b * SLOTS + k) * L_ + l];
#pragma unroll
    for (int a = 0; a < 4; ++a)
      acc[a] = fmaf(ar[(hg * 4 + a) * SLOTS + k], v, acc[a]);
  }
#pragma unroll
  for (int a = 0; a < 4; ++a)
    vt[((long)b * H_ + hg * 4 + a) * L_ + l] = acc[a];
}

// o[b,h*128+d] = vt[b,h,:] . Wv_up[:,h*128+d] + bv_up[h*128+d]  (f64)
__global__ __launch_bounds__(128) void oproj_kernel(
    const float* __restrict__ vt, const float* __restrict__ Wkvu,
    const float* __restrict__ bkvu, float* __restrict__ o) {
  __shared__ float vs[L_];
  const int h = blockIdx.x, b = blockIdx.y, t = threadIdx.x;
  for (int i = t; i < L_ / 4; i += 128)
    ((float4*)vs)[i] = ((const float4*)(vt + ((long)b * H_ + h) * L_))[i];
  __syncthreads();
  const int col = h * DH_ + t;
  double acc = 0.0;
  for (int l = 0; l < L_; ++l)
    acc += (double)vs[l] * (double)Wkvu[(long)l * 4096 + 2048 + col];
  o[b * D_ + col] = (float)(acc + (double)bkvu[2048 + col]);
}

// out[b,n] = o[b,:] @ Wout[:,n] + bout[n]  (f64)
__global__ __launch_bounds__(128) void out_kernel(
    const float* __restrict__ o, const float* __restrict__ Wout,
    const float* __restrict__ bout, float* __restrict__ out) {
  __shared__ float os[D_];
  const int b = blockIdx.y, t = threadIdx.x;
  for (int i = t; i < D_ / 4; i += 128)
    ((float4*)os)[i] = ((const float4*)(o + (long)b * D_))[i];
  __syncthreads();
  const int n = blockIdx.x * 128 + t;
  double acc = 0.0;
  for (int d = 0; d < D_; ++d) acc += (double)os[d] * (double)Wout[(long)d * D_ + n];
  out[b * D_ + n] = (float)(acc + (double)bout[n]);
}

extern "C" void kernel_launch(void* const* d_in, const int* in_sizes, int n_in,
                              void* d_out, int out_size, void* d_ws, size_t ws_size,
                              hipStream_t stream) {
  const float* x    = (const float*)d_in[0];
  const float* Wq   = (const float*)d_in[1];
  const float* bq   = (const float*)d_in[2];
  const float* Wkvd = (const float*)d_in[3];
  const float* bkvd = (const float*)d_in[4];
  const float* Wqd  = (const float*)d_in[5];
  const float* bqd  = (const float*)d_in[6];
  const float* Wkvu = (const float*)d_in[7];
  const float* bkvu = (const float*)d_in[8];
  const float* Wo   = (const float*)d_in[9];
  const float* bo   = (const float*)d_in[10];
  float* out = (float*)d_out;

  char* p = (char*)d_ws;
  auto alloc = [&](size_t bytes) {
    char* r = p;
    p += (bytes + 255) & ~(size_t)255;
    return r;
  };
  float*  Kd       = (float*)alloc((size_t)B_ * S_ * L_ * 4);       // 134.2 MB
  ushort* Kq8      = (ushort*)alloc((size_t)B_ * S_ * L_ * 2);      // 67.1 MB
  float*  Vsel     = (float*)alloc((size_t)B_ * SLOTS * L_ * 4);    // 34.6 MB
  float*  scores   = (float*)alloc((size_t)B_ * S_ * 4);
  float*  qidx     = (float*)alloc((size_t)B_ * L_ * 4);
  int*    rowmap   = (int*)alloc((size_t)B_ * TOPK_ * 4);
  int*    rowmapE  = (int*)alloc((size_t)B_ * SLOTS * 4);
  float*  multE    = (float*)alloc((size_t)B_ * SLOTS * 4);
  float*  vstarF   = (float*)alloc((size_t)B_ * 4);
  int2*   riskyL   = (int2*)alloc((size_t)RCAP * 8);                // 1 MB
  int*    riskyCnt = (int*)alloc(256);
  int*    flagArr  = (int*)alloc((size_t)B_ * S_ * 4);              // 0.26 MB
  int*    extraR   = (int*)alloc((size_t)B_ * EXTCAP * 4);
  int*    extraCnt = (int*)alloc((size_t)B_ * 4);
  int*    cntI2O   = (int*)alloc((size_t)B_ * 4);
  float*  qv       = (float*)alloc((size_t)B_ * D_ * 4);
  float*  qt       = (float*)alloc((size_t)B_ * H_ * L_ * 4);
  float*  blog     = (float*)alloc((size_t)B_ * H_ * 4);
  float*  logits   = (float*)alloc((size_t)B_ * H_ * SLOTS * 4);
  float*  vt       = (float*)alloc((size_t)B_ * H_ * L_ * 4);
  float*  ov       = (float*)alloc((size_t)B_ * D_ * 4);
  (void)ws_size; (void)in_sizes; (void)n_in; (void)out_size;

  zero_kernel<<<(B_ * S_ + 255) / 256, 256, 0, stream>>>(flagArr, riskyCnt, extraCnt, cntI2O);
  // K_down = x @ Wkv_down[:, :512] + bkv_down[:512] via bf16-split MFMA;
  // Kq8 = e4m3(K_down) from the f32 value + risky midpoint records.
  gemm_mfma<true><<<dim3(2, (B_ * S_) / 128), 256, 0, stream>>>(
      x, Wkvd, 1024, bkvd, Kd, Kq8, nullptr, riskyL, riskyCnt);
  qidx_kernel<<<dim3(L_ / 128, B_), 128, 0, stream>>>(x, Wqd, bqd, qidx);
  scores_kernel<<<(B_ * S_) / 4, 256, 0, stream>>>(Kq8, qidx, scores);
  topk_kernel<<<B_, 256, 0, stream>>>(scores, rowmap, vstarF);
  // hedge: find disputed rows + counterparties, build extended rowmap/mults
  risky_eval<<<RCAP / 256, 256, 0, stream>>>(riskyL, riskyCnt, Kq8, qidx, scores, vstarF,
                                             flagArr, extraR, extraCnt, cntI2O);
  counterparty_kernel<<<B_, 256, 0, stream>>>(scores, rowmap, vstarF, flagArr, extraR, extraCnt, cntI2O);
  buildext_kernel<<<dim3((SLOTS + 255) / 256, B_), 256, 0, stream>>>(rowmap, extraR, extraCnt, flagArr, rowmapE, multE);
  // V_down at selected+hedged rows via MFMA
  gemm_mfma<false><<<dim3(2, (B_ * SLOTS) / 128), 256, 0, stream>>>(
      x, Wkvd + 512, 1024, bkvd + 512, Vsel, nullptr, rowmapE, nullptr, nullptr);
  // attention (up-projections folded)
  qproj_kernel<<<dim3(D_ / 128, B_), 128, 0, stream>>>(x, Wq, bq, qv);
  qt_kernel<<<dim3(H_, B_), 256, 0, stream>>>(qv, Wkvu, bkvu, qt, blog);
  logits_kernel<<<dim3(SLOTS / 16, B_), 256, 0, stream>>>(Kd, rowmapE, qt, blog, logits);
  softmax_kernel<<<B_ * H_, 256, 0, stream>>>(logits, multE);
  vt_kernel<<<dim3(L_ / 64, B_), 256, 0, stream>>>(Vsel, logits, vt);
  oproj_kernel<<<dim3(H_, B_), 128, 0, stream>>>(vt, Wkvu, bkvu, ov);
  out_kernel<<<dim3(D_ / 128, B_), 128, 0, stream>>>(ov, Wo, bo, out);
}

// Round 9
// 3665.171 us; speedup vs baseline: 1.8237x; 1.0315x over previous
//
#include <hip/hip_runtime.h>
#include <hip/hip_bf16.h>
#include <math.h>

#define B_ 8
#define S_ 8192
#define D_ 2048
#define L_ 512
#define H_ 16
#define DH_ 128
#define TOPK_ 2048
#define EXTCAP 24
#define SLOTS (TOPK_ + 64)     // 2112, multiple of 64 and 16
#define RCAP 131072
#define DELTA 6e-6f

typedef __attribute__((ext_vector_type(8))) short short8;
typedef __attribute__((ext_vector_type(4))) float f32x4;

// fp8 e4m3fn RNE quantize from float (matches ml_dtypes astype from f32)
__device__ __forceinline__ float q8(float x) {
  float ax = fabsf(x);
  if (!(ax >= 0.015625f)) return rintf(x * 512.0f) * 0.001953125f;
  int ee; frexpf(ax, &ee);
  float step = ldexpf(1.0f, ee - 4);
  return rintf(ldexpf(x, 4 - ee)) * step;
}

// e4m3 quantize from float + midpoint analysis (for hedge detection)
__device__ __forceinline__ float q8_midf(float v, float* qflip, float* dist) {
  float av = fabsf(v);
  float step, u;
  if (!(av >= 0.015625f)) { step = 0.001953125f; u = v * 512.0f; }
  else { int ee; frexpf(av, &ee); step = ldexpf(1.0f, ee - 4); u = ldexpf(v, 4 - ee); }
  float m = rintf(u);
  float f = u - m;
  *dist = (0.5f - fabsf(f)) * step;
  float sgn = (f >= 0.0f) ? 1.0f : -1.0f;
  *qflip = (m + sgn) * step;
  return m * step;
}

__device__ __forceinline__ float b2f(unsigned u) {
  return __uint_as_float(u << 16);        // bf16 bits -> f32 (exact)
}

// f32 -> bf16 RNE bits
__device__ __forceinline__ ushort bfr(float x) {
  unsigned u = __float_as_uint(x);
  return (ushort)((u + 0x7FFFu + ((u >> 16) & 1u)) >> 16);
}
__device__ __forceinline__ float uf(ushort h) {
  return __uint_as_float(((unsigned)h) << 16);
}
// 3-way bf16 split: x ~= hi + mid + lo, residual <= 2^-24 |x|
__device__ __forceinline__ void split3(float x, ushort& h, ushort& m, ushort& l) {
  h = bfr(x); float r = x - uf(h);
  m = bfr(r); float r2 = r - uf(m);
  l = bfr(r2);
}

__device__ __forceinline__ f32x4 mfma16(short8 a, short8 b, f32x4 c) {
  return __builtin_amdgcn_mfma_f32_16x16x32_bf16(a, b, c, 0, 0, 0);
}

#if __has_builtin(__builtin_amdgcn_global_load_lds)
#define HAS_GLL 1
__device__ __forceinline__ void gload_lds16(const void* g, void* l) {
  __builtin_amdgcn_global_load_lds(
      (const __attribute__((address_space(1))) void*)g,
      (__attribute__((address_space(3))) void*)l, 16, 0, 0);
}
#else
#define HAS_GLL 0
#endif

__global__ __launch_bounds__(256) void zero_kernel(
    int* flag, int* riskyCnt, int* extraCnt, int* cntI2O) {
  int i = blockIdx.x * 256 + threadIdx.x;
  if (i < B_ * S_) flag[i] = 0;
  if (i == 0) *riskyCnt = 0;
  if (i < B_) { extraCnt[i] = 0; cntI2O[i] = 0; }
}

// Pre-split Wkv_down (2048 x 1024 f32) into 3 bf16 planes in the GEMM's
// LDS-ready layout: Wsp[T][kblk(64)][kb(4)][col(1024)][8 elems], so a GEMM
// block's (T,kb) B-slice is 4KB contiguous -> one global_load_lds per wave set.
__global__ __launch_bounds__(256) void wsplit_kernel(
    const float* __restrict__ W, ushort* __restrict__ Wsp) {
  const int c = blockIdx.x * 256 + threadIdx.x;   // col 0..1023
  const int kblk = blockIdx.y;                    // 0..63
  float xe[32];
#pragma unroll
  for (int e = 0; e < 32; ++e) xe[e] = W[(long)(kblk * 32 + e) * 1024 + c];
#pragma unroll
  for (int kb = 0; kb < 4; ++kb) {
    ushort Hh[8], Mm[8], Ll[8];
#pragma unroll
    for (int e = 0; e < 8; ++e) split3(xe[kb * 8 + e], Hh[e], Mm[e], Ll[e]);
    *(short8*)&Wsp[((((long)0 * 64 + kblk) * 4 + kb) * 1024 + c) * 8] = *(short8*)Hh;
    *(short8*)&Wsp[((((long)1 * 64 + kblk) * 4 + kb) * 1024 + c) * 8] = *(short8*)Mm;
    *(short8*)&Wsp[((((long)2 * 64 + kblk) * 4 + kb) * 1024 + c) * 8] = *(short8*)Ll;
  }
}

#define AS_IDX(T, kb, r) ((((T)*4 + (kb)) * 128 + (r)) * 8)
#define BS_IDX(T, kb, n) ((((T)*4 + (kb)) * 256 + (n)) * 8)

// MFMA GEMM via 3-way bf16 split (6 product terms), fp32 accumulate.
// C[m, n0..n0+255] = X[row(m), :2048] @ W[:, colbase+n] + bias[n]  (f32)
// B operand comes PRE-SPLIT from Wsp (wsplit_kernel layout) via
// global_load_lds — no B-side VALU in the loop. A split in-kernel.
// Tile 128x256, BK=32, 256 thr (4 waves, 2x2 wave grid, 64x128 per wave).
// QUANT: emit Cq8 = e4m3(C) as bf16 bits + risky midpoint records.
template <bool QUANT>
__global__ __launch_bounds__(256) void gemm_mfma(
    const float* __restrict__ X, const ushort* __restrict__ Wsp, int colbase,
    const float* __restrict__ bias, float* __restrict__ C,
    ushort* __restrict__ Cq8, const int* __restrict__ rowmap,
    int2* __restrict__ riskyList, int* __restrict__ riskyCnt) {
  __shared__ __align__(16) ushort As[3 * 4 * 128 * 8];   // 24 KB
  __shared__ __align__(16) ushort Bs[3 * 4 * 256 * 8];   // 48 KB
  const int tid = threadIdx.x;
  const int m0 = blockIdx.y * 128;
  const int n0 = blockIdx.x * 256;
  // A staging assignment: 2 threads/row, 16 k each
  const int ar_ = tid >> 1;
  const int kh = (tid & 1) << 4;
  const int arow = rowmap ? rowmap[m0 + ar_] : (m0 + ar_);
  const float* aptr = X + (long)arow * D_ + kh;
  const int cb = colbase + n0;        // global col of this block's col 0
  const int w64 = tid & ~63;          // wave-uniform lane base

  f32x4 acc[4][8];
#pragma unroll
  for (int i = 0; i < 4; ++i)
#pragma unroll
    for (int j = 0; j < 8; ++j) acc[i][j] = (f32x4){0.f, 0.f, 0.f, 0.f};

  const int w = tid >> 6, lane = tid & 63;
  const int wm = (w & 1) * 64, wn = (w >> 1) * 128;
  const int lr = lane & 15, lq = lane >> 4;

  for (int k0 = 0; k0 < D_; k0 += 32) {
    const int kblk = k0 >> 5;
    // A global loads to regs
    float4 v0 = *(const float4*)(aptr + k0);
    float4 v1 = *(const float4*)(aptr + k0 + 4);
    float4 v2 = *(const float4*)(aptr + k0 + 8);
    float4 v3 = *(const float4*)(aptr + k0 + 12);

    __syncthreads();   // previous iteration's LDS reads complete

    // B: pre-split planes -> LDS, 3T x 4kb, 4KB per call-site (256 thr x 16B)
#pragma unroll
    for (int T = 0; T < 3; ++T)
#pragma unroll
      for (int kb = 0; kb < 4; ++kb) {
        const ushort* g = Wsp + ((((long)T * 64 + kblk) * 4 + kb) * 1024 + cb + tid) * 8;
#if HAS_GLL
        gload_lds16(g, &Bs[(((T * 4 + kb) * 256) + w64) * 8]);
#else
        *(short8*)&Bs[BS_IDX(T, kb, tid)] = *(const short8*)g;
#endif
      }

    // A: split & write (thread covers row ar_, k = kh..kh+15 -> 2 kb groups)
    {
      float xe[16] = {v0.x, v0.y, v0.z, v0.w, v1.x, v1.y, v1.z, v1.w,
                      v2.x, v2.y, v2.z, v2.w, v3.x, v3.y, v3.z, v3.w};
      const int kb0 = (tid & 1) * 2;
#pragma unroll
      for (int j8 = 0; j8 < 2; ++j8) {
        ushort Hh[8], Mm[8], Ll[8];
#pragma unroll
        for (int e = 0; e < 8; ++e) split3(xe[j8 * 8 + e], Hh[e], Mm[e], Ll[e]);
        *(short8*)&As[AS_IDX(0, kb0 + j8, ar_)] = *(short8*)Hh;
        *(short8*)&As[AS_IDX(1, kb0 + j8, ar_)] = *(short8*)Mm;
        *(short8*)&As[AS_IDX(2, kb0 + j8, ar_)] = *(short8*)Ll;
      }
    }
    __syncthreads();   // drains ds_writes AND global_load_lds (vmcnt+lgkm)

    // MFMA: A frags (4 m-frags x 3 terms), loop n-frags
    short8 af[4][3];
#pragma unroll
    for (int mf = 0; mf < 4; ++mf)
#pragma unroll
      for (int T = 0; T < 3; ++T)
        af[mf][T] = *(const short8*)&As[AS_IDX(T, lq, wm + mf * 16 + lr)];
#pragma unroll
    for (int nf = 0; nf < 8; ++nf) {
      short8 bh = *(const short8*)&Bs[BS_IDX(0, lq, wn + nf * 16 + lr)];
      short8 bm = *(const short8*)&Bs[BS_IDX(1, lq, wn + nf * 16 + lr)];
      short8 bl = *(const short8*)&Bs[BS_IDX(2, lq, wn + nf * 16 + lr)];
#pragma unroll
      for (int mf = 0; mf < 4; ++mf) {
        f32x4 c = acc[mf][nf];
        c = mfma16(af[mf][0], bh, c);   // hh
        c = mfma16(af[mf][0], bm, c);   // hm
        c = mfma16(af[mf][1], bh, c);   // mh
        c = mfma16(af[mf][0], bl, c);   // hl
        c = mfma16(af[mf][2], bh, c);   // lh
        c = mfma16(af[mf][1], bm, c);   // mm
        acc[mf][nf] = c;
      }
    }
  }

  // epilogue: D layout col = lane&15, row = (lane>>4)*4 + i  [m89-verified]
#pragma unroll
  for (int nf = 0; nf < 8; ++nf) {
    const int ng = n0 + wn + nf * 16 + lr;
    const float bb = bias[ng];
#pragma unroll
    for (int mf = 0; mf < 4; ++mf) {
      const int mg = m0 + wm + mf * 16 + lq * 4;
#pragma unroll
      for (int i = 0; i < 4; ++i) {
        float v = acc[mf][nf][i] + bb;
        const long crow = (long)(mg + i);
        C[crow * L_ + ng] = v;
        if (QUANT) {
          float qflip, dist;
          float q = q8_midf(v, &qflip, &dist);
          Cq8[crow * L_ + ng] = (ushort)(__float_as_uint(q) >> 16);
          if (dist < DELTA) {
            int idx = atomicAdd(riskyCnt, 1);
            if (idx < RCAP) {
              unsigned qbits = __float_as_uint(qflip) >> 16;
              riskyList[idx] = make_int2((int)crow, (ng << 16) | (int)qbits);
            }
          }
        }
      }
    }
  }
}

// q_idx[b,l] = sum_d q8(x[b,-1,d]) * q8(Wq_down[d,l]) + q8(bq_down[l])  (f64)
__global__ __launch_bounds__(128) void qidx_kernel(
    const float* __restrict__ x, const float* __restrict__ Wqd,
    const float* __restrict__ bqd, float* __restrict__ qidx) {
  __shared__ float qs[D_];
  const int b = blockIdx.y;
  const int t = threadIdx.x;
  const float* xr = x + ((long)b * S_ + (S_ - 1)) * D_;
  for (int i = t; i < D_ / 4; i += 128) {
    float4 v = ((const float4*)xr)[i];
    qs[i * 4 + 0] = q8(v.x); qs[i * 4 + 1] = q8(v.y);
    qs[i * 4 + 2] = q8(v.z); qs[i * 4 + 3] = q8(v.w);
  }
  __syncthreads();
  const int l = blockIdx.x * 128 + t;
  double acc = 0.0;
  for (int d = 0; d < D_; ++d)
    acc += (double)qs[d] * (double)q8(Wqd[(long)d * L_ + l]);
  qidx[b * L_ + l] = (float)(acc + (double)q8(bqd[l]));
}

// scores[b,s] = relu( sum_l qidx[b,l] * Kq8[b,s,l] )  (f32, wave per row)
__global__ __launch_bounds__(256) void scores_kernel(
    const ushort* __restrict__ Kq8, const float* __restrict__ qidx,
    float* __restrict__ scores) {
  __shared__ float qs[L_];
  const int m0 = blockIdx.x * 4;
  const int b = m0 >> 13;
  const int t = threadIdx.x;
  if (t < 128) ((float4*)qs)[t] = ((const float4*)(qidx + b * L_))[t];
  __syncthreads();
  const int wave = t >> 6, lane = t & 63;
  const long m = m0 + wave;
  uint4 rv = *(const uint4*)(Kq8 + m * L_ + lane * 8);
  const float* q = qs + lane * 8;
  float p = 0.f;
  p = fmaf(q[0], b2f(rv.x & 0xffffu), p);
  p = fmaf(q[1], b2f(rv.x >> 16), p);
  p = fmaf(q[2], b2f(rv.y & 0xffffu), p);
  p = fmaf(q[3], b2f(rv.y >> 16), p);
  p = fmaf(q[4], b2f(rv.z & 0xffffu), p);
  p = fmaf(q[5], b2f(rv.z >> 16), p);
  p = fmaf(q[6], b2f(rv.w & 0xffffu), p);
  p = fmaf(q[7], b2f(rv.w >> 16), p);
#pragma unroll
  for (int off = 32; off >= 1; off >>= 1) p += __shfl_xor(p, off, 64);
  if (lane == 0) scores[m] = (p > 0.f) ? p : 0.f;   // force +0
}

// deterministic top-k per batch; also emits vstar (k-th value) per batch
__global__ __launch_bounds__(256) void topk_kernel(
    const float* __restrict__ scores, int* __restrict__ rowmap,
    float* __restrict__ vstarF) {
  __shared__ unsigned su[S_];
  __shared__ int red[256];
  __shared__ int cgt_sh;
  const int b = blockIdx.x, t = threadIdx.x;
  for (int i = t; i < S_; i += 256) su[i] = __float_as_uint(scores[(long)b * S_ + i]);
  __syncthreads();
  unsigned prefix = 0u;
  for (int bit = 30; bit >= 0; --bit) {
    unsigned cand = prefix | (1u << bit);
    int c = 0;
    for (int i = t; i < S_; i += 256) c += (su[i] >= cand) ? 1 : 0;
    red[t] = c;
    __syncthreads();
    for (int off = 128; off > 0; off >>= 1) {
      if (t < off) red[t] += red[t + off];
      __syncthreads();
    }
    if (red[0] >= TOPK_) prefix = cand;
    __syncthreads();
  }
  const unsigned vstar = prefix;
  if (t == 0) vstarF[b] = __uint_as_float(vstar);
  const int c0 = t * 32;
  int cnt = 0;
  for (int i = 0; i < 32; ++i) cnt += (su[c0 + i] > vstar) ? 1 : 0;
  red[t] = cnt;
  __syncthreads();
  if (t == 0) {
    int run = 0;
    for (int i = 0; i < 256; ++i) { int c = red[i]; red[i] = run; run += c; }
    cgt_sh = run;
  }
  __syncthreads();
  int pos = red[t];
  for (int i = 0; i < 32; ++i)
    if (su[c0 + i] > vstar) rowmap[b * TOPK_ + pos++] = b * S_ + c0 + i;
  if (t == 0) {
    int cnt2 = cgt_sh;
    for (int s = 0; s < S_ && cnt2 < TOPK_; ++s)
      if (su[s] == vstar) rowmap[b * TOPK_ + cnt2++] = b * S_ + s;
  }
}

// For each risky cell: does flipping it change its row's IN/OUT status?
__global__ __launch_bounds__(256) void risky_eval(
    const int2* __restrict__ list, const int* __restrict__ riskyCnt,
    const ushort* __restrict__ Kq8, const float* __restrict__ qidx,
    const float* __restrict__ scores, const float* __restrict__ vstarF,
    int* __restrict__ flag, int* __restrict__ extraRows,
    int* __restrict__ extraCnt, int* __restrict__ cntI2O) {
  int i = blockIdx.x * 256 + threadIdx.x;
  int n = min(*riskyCnt, RCAP);
  if (i >= n) return;
  int row = list[i].x;
  int l = list[i].y >> 16;
  float qflip = b2f((unsigned)(list[i].y & 0xffff));
  int b = row >> 13;
  float qorig = b2f((unsigned)Kq8[(long)row * L_ + l]);
  float shift = qidx[b * L_ + l] * (qflip - qorig);
  float s = scores[row];
  float vs = vstarF[b];
  bool in0 = (s >= vs);
  bool in1 = (s + shift >= vs);
  if (in0 != in1) {
    if (atomicCAS(&flag[row], 0, 1) == 0) {       // claim once per row
      if (in0) {
        atomicAdd(&cntI2O[b], 1);                 // IN row at risk of dropping
      } else {
        int e = atomicAdd(&extraCnt[b], 1);       // OUT row at risk of entering
        if (e < EXTCAP) extraRows[b * EXTCAP + e] = row;
      }
    }
  }
}

// Per batch: hedge counterparties — nA min-score IN rows, nD max-score OUT rows
__global__ __launch_bounds__(256) void counterparty_kernel(
    const float* __restrict__ scores, const int* __restrict__ rowmap,
    const float* __restrict__ vstarF, int* __restrict__ flag,
    int* __restrict__ extraRows, int* __restrict__ extraCnt,
    const int* __restrict__ cntI2O) {
  __shared__ float bv[256];
  __shared__ int bi[256];
  const int b = blockIdx.x, t = threadIdx.x;
  const float vs = vstarF[b];
  const int nA = min(extraCnt[b], EXTCAP);
  const int nD = min(cntI2O[b], EXTCAP);
  for (int pass = 0; pass < nA; ++pass) {
    float best = 3.4e38f; int besti = -1;
    for (int k = t; k < TOPK_; k += 256) {
      int r = rowmap[b * TOPK_ + k];
      if (!flag[r]) { float s = scores[r]; if (s < best) { best = s; besti = r; } }
    }
    bv[t] = best; bi[t] = besti; __syncthreads();
    for (int off = 128; off > 0; off >>= 1) {
      if (t < off && bv[t + off] < bv[t]) { bv[t] = bv[t + off]; bi[t] = bi[t + off]; }
      __syncthreads();
    }
    if (t == 0 && bi[0] >= 0) flag[bi[0]] = 1;
    __syncthreads();
  }
  for (int pass = 0; pass < nD; ++pass) {
    float best = -3.4e38f; int besti = -1;
    for (int s0 = t; s0 < S_; s0 += 256) {
      int r = b * S_ + s0;
      float s = scores[r];
      if (s < vs && !flag[r] && s > best) { best = s; besti = r; }
    }
    bv[t] = best; bi[t] = besti; __syncthreads();
    for (int off = 128; off > 0; off >>= 1) {
      if (t < off && bv[t + off] > bv[t]) { bv[t] = bv[t + off]; bi[t] = bi[t + off]; }
      __syncthreads();
    }
    if (t == 0 && bi[0] >= 0) {
      flag[bi[0]] = 1;
      int e = extraCnt[b];
      if (e < EXTCAP) { extraRows[b * EXTCAP + e] = bi[0]; extraCnt[b] = e + 1; }
    }
    __syncthreads();
  }
}

// rowmapExt[b][SLOTS] = rowmap(2048) + extras + pads; multExt = 1/0.5/0
__global__ __launch_bounds__(256) void buildext_kernel(
    const int* __restrict__ rowmap, const int* __restrict__ extraRows,
    const int* __restrict__ extraCnt, const int* __restrict__ flag,
    int* __restrict__ rowmapExt, float* __restrict__ multExt) {
  const int b = blockIdx.y;
  const int k = blockIdx.x * 256 + threadIdx.x;
  if (k >= SLOTS) return;
  const int tot = min(extraCnt[b], EXTCAP);
  int row; float m;
  if (k < TOPK_) { row = rowmap[b * TOPK_ + k]; m = flag[row] ? 0.5f : 1.0f; }
  else if (k - TOPK_ < tot) { row = extraRows[b * EXTCAP + (k - TOPK_)]; m = 0.5f; }
  else { row = b * S_; m = 0.0f; }
  rowmapExt[b * SLOTS + k] = row;
  multExt[b * SLOTS + k] = m;
}

// q[b,:] = x[b,-1,:] @ Wq + bq  (f64)
__global__ __launch_bounds__(128) void qproj_kernel(
    const float* __restrict__ x, const float* __restrict__ Wq,
    const float* __restrict__ bq, float* __restrict__ q) {
  __shared__ float xs[D_];
  const int b = blockIdx.y, t = threadIdx.x;
  const float* xr = x + ((long)b * S_ + (S_ - 1)) * D_;
  for (int i = t; i < D_ / 4; i += 128) ((float4*)xs)[i] = ((const float4*)xr)[i];
  __syncthreads();
  const int n = blockIdx.x * 128 + t;
  double acc = 0.0;
  for (int d = 0; d < D_; ++d) acc += (double)xs[d] * (double)Wq[(long)d * D_ + n];
  q[b * D_ + n] = (float)(acc + (double)bq[n]);
}

// qt[b,h,l] = sum_d q[b,h*128+d] * Wk_up[l,h*128+d];  blog[b,h] = q_h . bk_up_h
__global__ __launch_bounds__(256) void qt_kernel(
    const float* __restrict__ q, const float* __restrict__ Wkvu,
    const float* __restrict__ bkvu, float* __restrict__ qt,
    float* __restrict__ blog) {
  __shared__ float qh[DH_];
  __shared__ double red[DH_];
  const int h = blockIdx.x, b = blockIdx.y, t = threadIdx.x;
  if (t < DH_) qh[t] = q[b * D_ + h * DH_ + t];
  __syncthreads();
  for (int l = t; l < L_; l += 256) {
    const float* wr = Wkvu + (long)l * 4096 + h * DH_;
    double acc = 0.0;
    for (int d = 0; d < DH_; d += 4) {
      float4 w4 = *(const float4*)(wr + d);
      acc += (double)qh[d] * (double)w4.x + (double)qh[d + 1] * (double)w4.y
           + (double)qh[d + 2] * (double)w4.z + (double)qh[d + 3] * (double)w4.w;
    }
    qt[((long)b * H_ + h) * L_ + l] = (float)acc;
  }
  if (t < DH_) red[t] = (double)qh[t] * (double)bkvu[h * DH_ + t];
  __syncthreads();
  if (t == 0) {
    double s = 0.0;
    for (int i = 0; i < DH_; ++i) s += red[i];
    blog[b * H_ + h] = (float)s;
  }
}

// logits[b,h,k] over SLOTS entries via rowmapExt  (f64)
__global__ __launch_bounds__(256) void logits_kernel(
    const float* __restrict__ Kd, const int* __restrict__ rowmapExt,
    const float* __restrict__ qt, const float* __restrict__ blog,
    float* __restrict__ logits) {
  const int b = blockIdx.y;
  const int k = blockIdx.x * 16 + (threadIdx.x >> 4);
  const int h = threadIdx.x & 15;
  const float* kr = Kd + (long)rowmapExt[b * SLOTS + k] * L_;
  const float* qr = qt + ((long)b * H_ + h) * L_;
  double acc = 0.0;
  for (int l = 0; l < L_; l += 4) {
    float4 kv = *(const float4*)(kr + l);
    acc += (double)qr[l] * (double)kv.x + (double)qr[l + 1] * (double)kv.y
         + (double)qr[l + 2] * (double)kv.z + (double)qr[l + 3] * (double)kv.w;
  }
  logits[((long)b * H_ + h) * SLOTS + k] =
      (float)((acc + (double)blog[b * H_ + h]) * 0.088388347648318447);
}

// softmax over SLOTS with per-slot multipliers (hedged rows 0.5, pads 0)
__global__ __launch_bounds__(256) void softmax_kernel(
    float* __restrict__ logits, const float* __restrict__ multExt) {
  __shared__ double red[256];
  __shared__ float redf[256];
  const int bh = blockIdx.x;
  const int b = bh >> 4;
  float* row = logits + (long)bh * SLOTS;
  const float* mult = multExt + b * SLOTS;
  const int t = threadIdx.x;
  float m = -3.4e38f;
  for (int i = t; i < SLOTS; i += 256) m = fmaxf(m, row[i]);
  redf[t] = m; __syncthreads();
  for (int off = 128; off > 0; off >>= 1) {
    if (t < off) redf[t] = fmaxf(redf[t], redf[t + off]);
    __syncthreads();
  }
  m = redf[0]; __syncthreads();
  double s = 0.0;
  for (int i = t; i < SLOTS; i += 256)
    s += (double)mult[i] * exp((double)(row[i] - m));
  red[t] = s; __syncthreads();
  for (int off = 128; off > 0; off >>= 1) {
    if (t < off) red[t] += red[t + off];
    __syncthreads();
  }
  const double inv = 1.0 / red[0];
  __syncthreads();
  for (int i = t; i < SLOTS; i += 256)
    row[i] = (float)((double)mult[i] * exp((double)(row[i] - m)) * inv);
}

// vt[b,h,l] = sum_k attn[b,h,k] * Vsel[b,k,l]  over SLOTS (f32)
__global__ __launch_bounds__(256) void vt_kernel(
    const float* __restrict__ Vsel, const float* __restrict__ attn,
    float* __restrict__ vt) {
  const int b = blockIdx.y;
  const int l = blockIdx.x * 64 + (threadIdx.x & 63);
  const int hg = threadIdx.x >> 6;
  float acc[4] = {0.f, 0.f, 0.f, 0.f};
  const float* ar = attn + (long)b * H_ * SLOTS;
#pragma unroll 4
  for (int k = 0; k < SLOTS; ++k) {
    float v = Vsel[((long)b * SLOTS + k) * L_ + l];
#pragma unroll
    for (int a = 0; a < 4; ++a)
      acc[a] = fmaf(ar[(hg * 4 + a) * SLOTS + k], v, acc[a]);
  }
#pragma unroll
  for (int a = 0; a < 4; ++a)
    vt[((long)b * H_ + hg * 4 + a) * L_ + l] = acc[a];
}

// o[b,h*128+d] = vt[b,h,:] . Wv_up[:,h*128+d] + bv_up[h*128+d]  (f64)
__global__ __launch_bounds__(128) void oproj_kernel(
    const float* __restrict__ vt, const float* __restrict__ Wkvu,
    const float* __restrict__ bkvu, float* __restrict__ o) {
  __shared__ float vs[L_];
  const int h = blockIdx.x, b = blockIdx.y, t = threadIdx.x;
  for (int i = t; i < L_ / 4; i += 128)
    ((float4*)vs)[i] = ((const float4*)(vt + ((long)b * H_ + h) * L_))[i];
  __syncthreads();
  const int col = h * DH_ + t;
  double acc = 0.0;
  for (int l = 0; l < L_; ++l)
    acc += (double)vs[l] * (double)Wkvu[(long)l * 4096 + 2048 + col];
  o[b * D_ + col] = (float)(acc + (double)bkvu[2048 + col]);
}

// out[b,n] = o[b,:] @ Wout[:,n] + bout[n]  (f64)
__global__ __launch_bounds__(128) void out_kernel(
    const float* __restrict__ o, const float* __restrict__ Wout,
    const float* __restrict__ bout, float* __restrict__ out) {
  __shared__ float os[D_];
  const int b = blockIdx.y, t = threadIdx.x;
  for (int i = t; i < D_ / 4; i += 128)
    ((float4*)os)[i] = ((const float4*)(o + (long)b * D_))[i];
  __syncthreads();
  const int n = blockIdx.x * 128 + t;
  double acc = 0.0;
  for (int d = 0; d < D_; ++d) acc += (double)os[d] * (double)Wout[(long)d * D_ + n];
  out[b * D_ + n] = (float)(acc + (double)bout[n]);
}

extern "C" void kernel_launch(void* const* d_in, const int* in_sizes, int n_in,
                              void* d_out, int out_size, void* d_ws, size_t ws_size,
                              hipStream_t stream) {
  const float* x    = (const float*)d_in[0];
  const float* Wq   = (const float*)d_in[1];
  const float* bq   = (const float*)d_in[2];
  const float* Wkvd = (const float*)d_in[3];
  const float* bkvd = (const float*)d_in[4];
  const float* Wqd  = (const float*)d_in[5];
  const float* bqd  = (const float*)d_in[6];
  const float* Wkvu = (const float*)d_in[7];
  const float* bkvu = (const float*)d_in[8];
  const float* Wo   = (const float*)d_in[9];
  const float* bo   = (const float*)d_in[10];
  float* out = (float*)d_out;

  char* p = (char*)d_ws;
  auto alloc = [&](size_t bytes) {
    char* r = p;
    p += (bytes + 255) & ~(size_t)255;
    return r;
  };
  float*  Kd       = (float*)alloc((size_t)B_ * S_ * L_ * 4);       // 134.2 MB
  ushort* Kq8      = (ushort*)alloc((size_t)B_ * S_ * L_ * 2);      // 67.1 MB
  float*  Vsel     = (float*)alloc((size_t)B_ * SLOTS * L_ * 4);    // 34.6 MB
  ushort* Wsp      = (ushort*)alloc((size_t)3 * 64 * 4 * 1024 * 8 * 2);  // 12.6 MB
  float*  scores   = (float*)alloc((size_t)B_ * S_ * 4);
  float*  qidx     = (float*)alloc((size_t)B_ * L_ * 4);
  int*    rowmap   = (int*)alloc((size_t)B_ * TOPK_ * 4);
  int*    rowmapE  = (int*)alloc((size_t)B_ * SLOTS * 4);
  float*  multE    = (float*)alloc((size_t)B_ * SLOTS * 4);
  float*  vstarF   = (float*)alloc((size_t)B_ * 4);
  int2*   riskyL   = (int2*)alloc((size_t)RCAP * 8);                // 1 MB
  int*    riskyCnt = (int*)alloc(256);
  int*    flagArr  = (int*)alloc((size_t)B_ * S_ * 4);              // 0.26 MB
  int*    extraR   = (int*)alloc((size_t)B_ * EXTCAP * 4);
  int*    extraCnt = (int*)alloc((size_t)B_ * 4);
  int*    cntI2O   = (int*)alloc((size_t)B_ * 4);
  float*  qv       = (float*)alloc((size_t)B_ * D_ * 4);
  float*  qt       = (float*)alloc((size_t)B_ * H_ * L_ * 4);
  float*  blog     = (float*)alloc((size_t)B_ * H_ * 4);
  float*  logits   = (float*)alloc((size_t)B_ * H_ * SLOTS * 4);
  float*  vt       = (float*)alloc((size_t)B_ * H_ * L_ * 4);
  float*  ov       = (float*)alloc((size_t)B_ * D_ * 4);
  (void)ws_size; (void)in_sizes; (void)n_in; (void)out_size;

  zero_kernel<<<(B_ * S_ + 255) / 256, 256, 0, stream>>>(flagArr, riskyCnt, extraCnt, cntI2O);
  // one-shot: pre-split Wkv_down (both halves) into MFMA-ready bf16 planes
  wsplit_kernel<<<dim3(4, 64), 256, 0, stream>>>(Wkvd, Wsp);
  // K_down = x @ Wkv_down[:, :512] + bkv_down[:512] via bf16-split MFMA;
  // Kq8 = e4m3(K_down) from the f32 value + risky midpoint records.
  gemm_mfma<true><<<dim3(2, (B_ * S_) / 128), 256, 0, stream>>>(
      x, Wsp, 0, bkvd, Kd, Kq8, nullptr, riskyL, riskyCnt);
  qidx_kernel<<<dim3(L_ / 128, B_), 128, 0, stream>>>(x, Wqd, bqd, qidx);
  scores_kernel<<<(B_ * S_) / 4, 256, 0, stream>>>(Kq8, qidx, scores);
  topk_kernel<<<B_, 256, 0, stream>>>(scores, rowmap, vstarF);
  // hedge: find disputed rows + counterparties, build extended rowmap/mults
  risky_eval<<<RCAP / 256, 256, 0, stream>>>(riskyL, riskyCnt, Kq8, qidx, scores, vstarF,
                                             flagArr, extraR, extraCnt, cntI2O);
  counterparty_kernel<<<B_, 256, 0, stream>>>(scores, rowmap, vstarF, flagArr, extraR, extraCnt, cntI2O);
  buildext_kernel<<<dim3((SLOTS + 255) / 256, B_), 256, 0, stream>>>(rowmap, extraR, extraCnt, flagArr, rowmapE, multE);
  // V_down at selected+hedged rows via MFMA (cols 512..1023 of Wkv_down)
  gemm_mfma<false><<<dim3(2, (B_ * SLOTS) / 128), 256, 0, stream>>>(
      x, Wsp, 512, bkvd + 512, Vsel, nullptr, rowmapE, nullptr, nullptr);
  // attention (up-projections folded)
  qproj_kernel<<<dim3(D_ / 128, B_), 128, 0, stream>>>(x, Wq, bq, qv);
  qt_kernel<<<dim3(H_, B_), 256, 0, stream>>>(qv, Wkvu, bkvu, qt, blog);
  logits_kernel<<<dim3(SLOTS / 16, B_), 256, 0, stream>>>(Kd, rowmapE, qt, blog, logits);
  softmax_kernel<<<B_ * H_, 256, 0, stream>>>(logits, multE);
  vt_kernel<<<dim3(L_ / 64, B_), 256, 0, stream>>>(Vsel, logits, vt);
  oproj_kernel<<<dim3(H_, B_), 128, 0, stream>>>(vt, Wkvu, bkvu, ov);
  out_kernel<<<dim3(D_ / 128, B_), 128, 0, stream>>>(ov, Wo, bo, out);
}

// Round 10
// 3426.933 us; speedup vs baseline: 1.9505x; 1.0695x over previous
//
#include <hip/hip_runtime.h>
#include <hip/hip_bf16.h>
#include <math.h>

#define B_ 8
#define S_ 8192
#define D_ 2048
#define L_ 512
#define H_ 16
#define DH_ 128
#define TOPK_ 2048
#define EXTCAP 24
#define SLOTS (TOPK_ + 64)     // 2112, multiple of 64 and 16
#define RCAP 131072
#define DELTA 6e-6f

typedef __attribute__((ext_vector_type(8))) short short8;
typedef __attribute__((ext_vector_type(4))) float f32x4;

// fp8 e4m3fn RNE quantize from float (matches ml_dtypes astype from f32)
__device__ __forceinline__ float q8(float x) {
  float ax = fabsf(x);
  if (!(ax >= 0.015625f)) return rintf(x * 512.0f) * 0.001953125f;
  int ee; frexpf(ax, &ee);
  float step = ldexpf(1.0f, ee - 4);
  return rintf(ldexpf(x, 4 - ee)) * step;
}

// e4m3 quantize from float + midpoint analysis (for hedge detection)
__device__ __forceinline__ float q8_midf(float v, float* qflip, float* dist) {
  float av = fabsf(v);
  float step, u;
  if (!(av >= 0.015625f)) { step = 0.001953125f; u = v * 512.0f; }
  else { int ee; frexpf(av, &ee); step = ldexpf(1.0f, ee - 4); u = ldexpf(v, 4 - ee); }
  float m = rintf(u);
  float f = u - m;
  *dist = (0.5f - fabsf(f)) * step;
  float sgn = (f >= 0.0f) ? 1.0f : -1.0f;
  *qflip = (m + sgn) * step;
  return m * step;
}

__device__ __forceinline__ float b2f(unsigned u) {
  return __uint_as_float(u << 16);        // bf16 bits -> f32 (exact)
}

// f32 -> bf16 RNE bits
__device__ __forceinline__ ushort bfr(float x) {
  unsigned u = __float_as_uint(x);
  return (ushort)((u + 0x7FFFu + ((u >> 16) & 1u)) >> 16);
}
__device__ __forceinline__ float uf(ushort h) {
  return __uint_as_float(((unsigned)h) << 16);
}
// 3-way bf16 split: x ~= hi + mid + lo, residual <= 2^-24 |x|
__device__ __forceinline__ void split3(float x, ushort& h, ushort& m, ushort& l) {
  h = bfr(x); float r = x - uf(h);
  m = bfr(r); float r2 = r - uf(m);
  l = bfr(r2);
}

__device__ __forceinline__ f32x4 mfma16(short8 a, short8 b, f32x4 c) {
  return __builtin_amdgcn_mfma_f32_16x16x32_bf16(a, b, c, 0, 0, 0);
}

#if __has_builtin(__builtin_amdgcn_global_load_lds)
#define HAS_GLL 1
__device__ __forceinline__ void gload_lds16(const void* g, void* l) {
  __builtin_amdgcn_global_load_lds(
      (const __attribute__((address_space(1))) void*)g,
      (__attribute__((address_space(3))) void*)l, 16, 0, 0);
}
#else
#define HAS_GLL 0
#endif

__global__ __launch_bounds__(256) void zero_kernel(
    int* flag, int* riskyCnt, int* extraCnt, int* cntI2O) {
  int i = blockIdx.x * 256 + threadIdx.x;
  if (i < B_ * S_) flag[i] = 0;
  if (i == 0) *riskyCnt = 0;
  if (i < B_) { extraCnt[i] = 0; cntI2O[i] = 0; }
}

// Pre-split Wkv_down (2048 x 1024 f32) into 3 bf16 planes in the GEMM's
// LDS-ready layout: Wsp[T][kblk(64)][kb(4)][col(1024)][8 elems].
__global__ __launch_bounds__(256) void wsplit_kernel(
    const float* __restrict__ W, ushort* __restrict__ Wsp) {
  const int c = blockIdx.x * 256 + threadIdx.x;   // col 0..1023
  const int kblk = blockIdx.y;                    // 0..63
  float xe[32];
#pragma unroll
  for (int e = 0; e < 32; ++e) xe[e] = W[(long)(kblk * 32 + e) * 1024 + c];
#pragma unroll
  for (int kb = 0; kb < 4; ++kb) {
    ushort Hh[8], Mm[8], Ll[8];
#pragma unroll
    for (int e = 0; e < 8; ++e) split3(xe[kb * 8 + e], Hh[e], Mm[e], Ll[e]);
    *(short8*)&Wsp[((((long)0 * 64 + kblk) * 4 + kb) * 1024 + c) * 8] = *(short8*)Hh;
    *(short8*)&Wsp[((((long)1 * 64 + kblk) * 4 + kb) * 1024 + c) * 8] = *(short8*)Mm;
    *(short8*)&Wsp[((((long)2 * 64 + kblk) * 4 + kb) * 1024 + c) * 8] = *(short8*)Ll;
  }
}

#define AS_IDX(T, kb, r) ((((T)*4 + (kb)) * 128 + (r)) * 8)
#define BS_IDX(T, kb, n) ((((T)*4 + (kb)) * 128 + (n)) * 8)

// MFMA GEMM via 3-way bf16 split (6 product terms), fp32 accumulate.
// C[m, n0..n0+127] = X[row(m), :2048] @ W[:, colbase+n] + bias[n]  (f32)
// Retiled 128x128 (wave tile 64x64, acc=64 regs, LDS 48KB) for >=2 blocks/CU.
// Per-C-element MFMA term order identical to previous rounds -> bit-identical.
template <bool QUANT>
__global__ __launch_bounds__(256, 2) void gemm_mfma(
    const float* __restrict__ X, const ushort* __restrict__ Wsp, int colbase,
    const float* __restrict__ bias, float* __restrict__ C,
    ushort* __restrict__ Cq8, const int* __restrict__ rowmap,
    int2* __restrict__ riskyList, int* __restrict__ riskyCnt) {
  __shared__ __align__(16) ushort As[3 * 4 * 128 * 8];   // 24 KB
  __shared__ __align__(16) ushort Bs[3 * 4 * 128 * 8];   // 24 KB
  const int tid = threadIdx.x;
  const int m0 = blockIdx.y * 128;
  const int n0 = blockIdx.x * 128;
  // A staging assignment: 2 threads/row, 16 k each
  const int ar_ = tid >> 1;
  const int kh = (tid & 1) << 4;
  const int arow = rowmap ? rowmap[m0 + ar_] : (m0 + ar_);
  const float* aptr = X + (long)arow * D_ + kh;
  const int cb = colbase + n0;        // global col of this block's col 0

  f32x4 acc[4][4];
#pragma unroll
  for (int i = 0; i < 4; ++i)
#pragma unroll
    for (int j = 0; j < 4; ++j) acc[i][j] = (f32x4){0.f, 0.f, 0.f, 0.f};

  const int w = tid >> 6, lane = tid & 63;
  const int wm = (w & 1) * 64, wn = (w >> 1) * 64;
  const int lr = lane & 15, lq = lane >> 4;

  // A prefetch for k0 = 0
  float4 v0 = *(const float4*)(aptr + 0);
  float4 v1 = *(const float4*)(aptr + 4);
  float4 v2 = *(const float4*)(aptr + 8);
  float4 v3 = *(const float4*)(aptr + 12);

  for (int k0 = 0; k0 < D_; k0 += 32) {
    const int kblk = k0 >> 5;

    __syncthreads();   // previous iteration's LDS reads complete

    // B: pre-split planes -> LDS. 12 slices (T,kb) x 128 cols x 16B = 24KB;
    // 24 x 1KB wave-chunks; wave w loads chunks w*6..w*6+5.
#pragma unroll
    for (int i = 0; i < 6; ++i) {
      const int c = w * 6 + i;          // 0..23
      const int s = c >> 1, half = c & 1;
      const int T = s >> 2, kb = s & 3;
      const ushort* g = Wsp + ((((long)T * 64 + kblk) * 4 + kb) * 1024 +
                               (long)cb + half * 64 + lane) * 8;
#if HAS_GLL
      gload_lds16(g, &Bs[(s * 128 + half * 64) * 8]);
#else
      *(short8*)&Bs[(s * 128 + half * 64 + lane) * 8] = *(const short8*)g;
#endif
    }

    // A: split current regs & write (row ar_, k = kh..kh+15 -> 2 kb groups)
    {
      float xe[16] = {v0.x, v0.y, v0.z, v0.w, v1.x, v1.y, v1.z, v1.w,
                      v2.x, v2.y, v2.z, v2.w, v3.x, v3.y, v3.z, v3.w};
      const int kb0 = (tid & 1) * 2;
#pragma unroll
      for (int j8 = 0; j8 < 2; ++j8) {
        ushort Hh[8], Mm[8], Ll[8];
#pragma unroll
        for (int e = 0; e < 8; ++e) split3(xe[j8 * 8 + e], Hh[e], Mm[e], Ll[e]);
        *(short8*)&As[AS_IDX(0, kb0 + j8, ar_)] = *(short8*)Hh;
        *(short8*)&As[AS_IDX(1, kb0 + j8, ar_)] = *(short8*)Mm;
        *(short8*)&As[AS_IDX(2, kb0 + j8, ar_)] = *(short8*)Ll;
      }
    }
    // A prefetch for next iteration (issued before barrier)
    if (k0 + 32 < D_) {
      v0 = *(const float4*)(aptr + k0 + 32);
      v1 = *(const float4*)(aptr + k0 + 36);
      v2 = *(const float4*)(aptr + k0 + 40);
      v3 = *(const float4*)(aptr + k0 + 44);
    }
    __syncthreads();   // drains ds_writes AND global_load_lds

    // MFMA: A frags (4 m-frags x 3 terms), loop n-frags
    short8 af[4][3];
#pragma unroll
    for (int mf = 0; mf < 4; ++mf)
#pragma unroll
      for (int T = 0; T < 3; ++T)
        af[mf][T] = *(const short8*)&As[AS_IDX(T, lq, wm + mf * 16 + lr)];
#pragma unroll
    for (int nf = 0; nf < 4; ++nf) {
      short8 bh = *(const short8*)&Bs[BS_IDX(0, lq, wn + nf * 16 + lr)];
      short8 bm = *(const short8*)&Bs[BS_IDX(1, lq, wn + nf * 16 + lr)];
      short8 bl = *(const short8*)&Bs[BS_IDX(2, lq, wn + nf * 16 + lr)];
#pragma unroll
      for (int mf = 0; mf < 4; ++mf) {
        f32x4 c = acc[mf][nf];
        c = mfma16(af[mf][0], bh, c);   // hh
        c = mfma16(af[mf][0], bm, c);   // hm
        c = mfma16(af[mf][1], bh, c);   // mh
        c = mfma16(af[mf][0], bl, c);   // hl
        c = mfma16(af[mf][2], bh, c);   // lh
        c = mfma16(af[mf][1], bm, c);   // mm
        acc[mf][nf] = c;
      }
    }
  }

  // epilogue: D layout col = lane&15, row = (lane>>4)*4 + i  [m89-verified]
#pragma unroll
  for (int nf = 0; nf < 4; ++nf) {
    const int ng = n0 + wn + nf * 16 + lr;
    const float bb = bias[ng];
#pragma unroll
    for (int mf = 0; mf < 4; ++mf) {
      const int mg = m0 + wm + mf * 16 + lq * 4;
#pragma unroll
      for (int i = 0; i < 4; ++i) {
        float v = acc[mf][nf][i] + bb;
        const long crow = (long)(mg + i);
        C[crow * L_ + ng] = v;
        if (QUANT) {
          float qflip, dist;
          float q = q8_midf(v, &qflip, &dist);
          Cq8[crow * L_ + ng] = (ushort)(__float_as_uint(q) >> 16);
          if (dist < DELTA) {
            int idx = atomicAdd(riskyCnt, 1);
            if (idx < RCAP) {
              unsigned qbits = __float_as_uint(qflip) >> 16;
              riskyList[idx] = make_int2((int)crow, (ng << 16) | (int)qbits);
            }
          }
        }
      }
    }
  }
}

// q_idx[b,l] = sum_d q8(x[b,-1,d]) * q8(Wq_down[d,l]) + q8(bq_down[l])  (f64)
__global__ __launch_bounds__(128) void qidx_kernel(
    const float* __restrict__ x, const float* __restrict__ Wqd,
    const float* __restrict__ bqd, float* __restrict__ qidx) {
  __shared__ float qs[D_];
  const int b = blockIdx.y;
  const int t = threadIdx.x;
  const float* xr = x + ((long)b * S_ + (S_ - 1)) * D_;
  for (int i = t; i < D_ / 4; i += 128) {
    float4 v = ((const float4*)xr)[i];
    qs[i * 4 + 0] = q8(v.x); qs[i * 4 + 1] = q8(v.y);
    qs[i * 4 + 2] = q8(v.z); qs[i * 4 + 3] = q8(v.w);
  }
  __syncthreads();
  const int l = blockIdx.x * 128 + t;
  double acc = 0.0;
  for (int d = 0; d < D_; ++d)
    acc += (double)qs[d] * (double)q8(Wqd[(long)d * L_ + l]);
  qidx[b * L_ + l] = (float)(acc + (double)q8(bqd[l]));
}

// scores[b,s] = relu( sum_l qidx[b,l] * Kq8[b,s,l] )  (f32, wave per row)
__global__ __launch_bounds__(256) void scores_kernel(
    const ushort* __restrict__ Kq8, const float* __restrict__ qidx,
    float* __restrict__ scores) {
  __shared__ float qs[L_];
  const int m0 = blockIdx.x * 4;
  const int b = m0 >> 13;
  const int t = threadIdx.x;
  if (t < 128) ((float4*)qs)[t] = ((const float4*)(qidx + b * L_))[t];
  __syncthreads();
  const int wave = t >> 6, lane = t & 63;
  const long m = m0 + wave;
  uint4 rv = *(const uint4*)(Kq8 + m * L_ + lane * 8);
  const float* q = qs + lane * 8;
  float p = 0.f;
  p = fmaf(q[0], b2f(rv.x & 0xffffu), p);
  p = fmaf(q[1], b2f(rv.x >> 16), p);
  p = fmaf(q[2], b2f(rv.y & 0xffffu), p);
  p = fmaf(q[3], b2f(rv.y >> 16), p);
  p = fmaf(q[4], b2f(rv.z & 0xffffu), p);
  p = fmaf(q[5], b2f(rv.z >> 16), p);
  p = fmaf(q[6], b2f(rv.w & 0xffffu), p);
  p = fmaf(q[7], b2f(rv.w >> 16), p);
#pragma unroll
  for (int off = 32; off >= 1; off >>= 1) p += __shfl_xor(p, off, 64);
  if (lane == 0) scores[m] = (p > 0.f) ? p : 0.f;   // force +0
}

// deterministic top-k per batch; also emits vstar (k-th value) per batch
__global__ __launch_bounds__(256) void topk_kernel(
    const float* __restrict__ scores, int* __restrict__ rowmap,
    float* __restrict__ vstarF) {
  __shared__ unsigned su[S_];
  __shared__ int red[256];
  __shared__ int cgt_sh;
  const int b = blockIdx.x, t = threadIdx.x;
  for (int i = t; i < S_; i += 256) su[i] = __float_as_uint(scores[(long)b * S_ + i]);
  __syncthreads();
  unsigned prefix = 0u;
  for (int bit = 30; bit >= 0; --bit) {
    unsigned cand = prefix | (1u << bit);
    int c = 0;
    for (int i = t; i < S_; i += 256) c += (su[i] >= cand) ? 1 : 0;
    red[t] = c;
    __syncthreads();
    for (int off = 128; off > 0; off >>= 1) {
      if (t < off) red[t] += red[t + off];
      __syncthreads();
    }
    if (red[0] >= TOPK_) prefix = cand;
    __syncthreads();
  }
  const unsigned vstar = prefix;
  if (t == 0) vstarF[b] = __uint_as_float(vstar);
  const int c0 = t * 32;
  int cnt = 0;
  for (int i = 0; i < 32; ++i) cnt += (su[c0 + i] > vstar) ? 1 : 0;
  red[t] = cnt;
  __syncthreads();
  if (t == 0) {
    int run = 0;
    for (int i = 0; i < 256; ++i) { int c = red[i]; red[i] = run; run += c; }
    cgt_sh = run;
  }
  __syncthreads();
  int pos = red[t];
  for (int i = 0; i < 32; ++i)
    if (su[c0 + i] > vstar) rowmap[b * TOPK_ + pos++] = b * S_ + c0 + i;
  if (t == 0) {
    int cnt2 = cgt_sh;
    for (int s = 0; s < S_ && cnt2 < TOPK_; ++s)
      if (su[s] == vstar) rowmap[b * TOPK_ + cnt2++] = b * S_ + s;
  }
}

// For each risky cell: does flipping it change its row's IN/OUT status?
__global__ __launch_bounds__(256) void risky_eval(
    const int2* __restrict__ list, const int* __restrict__ riskyCnt,
    const ushort* __restrict__ Kq8, const float* __restrict__ qidx,
    const float* __restrict__ scores, const float* __restrict__ vstarF,
    int* __restrict__ flag, int* __restrict__ extraRows,
    int* __restrict__ extraCnt, int* __restrict__ cntI2O) {
  int i = blockIdx.x * 256 + threadIdx.x;
  int n = min(*riskyCnt, RCAP);
  if (i >= n) return;
  int row = list[i].x;
  int l = list[i].y >> 16;
  float qflip = b2f((unsigned)(list[i].y & 0xffff));
  int b = row >> 13;
  float qorig = b2f((unsigned)Kq8[(long)row * L_ + l]);
  float shift = qidx[b * L_ + l] * (qflip - qorig);
  float s = scores[row];
  float vs = vstarF[b];
  bool in0 = (s >= vs);
  bool in1 = (s + shift >= vs);
  if (in0 != in1) {
    if (atomicCAS(&flag[row], 0, 1) == 0) {       // claim once per row
      if (in0) {
        atomicAdd(&cntI2O[b], 1);                 // IN row at risk of dropping
      } else {
        int e = atomicAdd(&extraCnt[b], 1);       // OUT row at risk of entering
        if (e < EXTCAP) extraRows[b * EXTCAP + e] = row;
      }
    }
  }
}

// Per batch: hedge counterparties — nA min-score IN rows, nD max-score OUT rows
__global__ __launch_bounds__(256) void counterparty_kernel(
    const float* __restrict__ scores, const int* __restrict__ rowmap,
    const float* __restrict__ vstarF, int* __restrict__ flag,
    int* __restrict__ extraRows, int* __restrict__ extraCnt,
    const int* __restrict__ cntI2O) {
  __shared__ float bv[256];
  __shared__ int bi[256];
  const int b = blockIdx.x, t = threadIdx.x;
  const float vs = vstarF[b];
  const int nA = min(extraCnt[b], EXTCAP);
  const int nD = min(cntI2O[b], EXTCAP);
  for (int pass = 0; pass < nA; ++pass) {
    float best = 3.4e38f; int besti = -1;
    for (int k = t; k < TOPK_; k += 256) {
      int r = rowmap[b * TOPK_ + k];
      if (!flag[r]) { float s = scores[r]; if (s < best) { best = s; besti = r; } }
    }
    bv[t] = best; bi[t] = besti; __syncthreads();
    for (int off = 128; off > 0; off >>= 1) {
      if (t < off && bv[t + off] < bv[t]) { bv[t] = bv[t + off]; bi[t] = bi[t + off]; }
      __syncthreads();
    }
    if (t == 0 && bi[0] >= 0) flag[bi[0]] = 1;
    __syncthreads();
  }
  for (int pass = 0; pass < nD; ++pass) {
    float best = -3.4e38f; int besti = -1;
    for (int s0 = t; s0 < S_; s0 += 256) {
      int r = b * S_ + s0;
      float s = scores[r];
      if (s < vs && !flag[r] && s > best) { best = s; besti = r; }
    }
    bv[t] = best; bi[t] = besti; __syncthreads();
    for (int off = 128; off > 0; off >>= 1) {
      if (t < off && bv[t + off] > bv[t]) { bv[t] = bv[t + off]; bi[t] = bi[t + off]; }
      __syncthreads();
    }
    if (t == 0 && bi[0] >= 0) {
      flag[bi[0]] = 1;
      int e = extraCnt[b];
      if (e < EXTCAP) { extraRows[b * EXTCAP + e] = bi[0]; extraCnt[b] = e + 1; }
    }
    __syncthreads();
  }
}

// rowmapExt[b][SLOTS] = rowmap(2048) + extras + pads; multExt = 1/0.5/0
__global__ __launch_bounds__(256) void buildext_kernel(
    const int* __restrict__ rowmap, const int* __restrict__ extraRows,
    const int* __restrict__ extraCnt, const int* __restrict__ flag,
    int* __restrict__ rowmapExt, float* __restrict__ multExt) {
  const int b = blockIdx.y;
  const int k = blockIdx.x * 256 + threadIdx.x;
  if (k >= SLOTS) return;
  const int tot = min(extraCnt[b], EXTCAP);
  int row; float m;
  if (k < TOPK_) { row = rowmap[b * TOPK_ + k]; m = flag[row] ? 0.5f : 1.0f; }
  else if (k - TOPK_ < tot) { row = extraRows[b * EXTCAP + (k - TOPK_)]; m = 0.5f; }
  else { row = b * S_; m = 0.0f; }
  rowmapExt[b * SLOTS + k] = row;
  multExt[b * SLOTS + k] = m;
}

// q[b,:] = x[b,-1,:] @ Wq + bq  (f64)
__global__ __launch_bounds__(128) void qproj_kernel(
    const float* __restrict__ x, const float* __restrict__ Wq,
    const float* __restrict__ bq, float* __restrict__ q) {
  __shared__ float xs[D_];
  const int b = blockIdx.y, t = threadIdx.x;
  const float* xr = x + ((long)b * S_ + (S_ - 1)) * D_;
  for (int i = t; i < D_ / 4; i += 128) ((float4*)xs)[i] = ((const float4*)xr)[i];
  __syncthreads();
  const int n = blockIdx.x * 128 + t;
  double acc = 0.0;
  for (int d = 0; d < D_; ++d) acc += (double)xs[d] * (double)Wq[(long)d * D_ + n];
  q[b * D_ + n] = (float)(acc + (double)bq[n]);
}

// qt[b,h,l] = sum_d q[b,h*128+d] * Wk_up[l,h*128+d];  blog[b,h] = q_h . bk_up_h
__global__ __launch_bounds__(256) void qt_kernel(
    const float* __restrict__ q, const float* __restrict__ Wkvu,
    const float* __restrict__ bkvu, float* __restrict__ qt,
    float* __restrict__ blog) {
  __shared__ float qh[DH_];
  __shared__ double red[DH_];
  const int h = blockIdx.x, b = blockIdx.y, t = threadIdx.x;
  if (t < DH_) qh[t] = q[b * D_ + h * DH_ + t];
  __syncthreads();
  for (int l = t; l < L_; l += 256) {
    const float* wr = Wkvu + (long)l * 4096 + h * DH_;
    double acc = 0.0;
    for (int d = 0; d < DH_; d += 4) {
      float4 w4 = *(const float4*)(wr + d);
      acc += (double)qh[d] * (double)w4.x + (double)qh[d + 1] * (double)w4.y
           + (double)qh[d + 2] * (double)w4.z + (double)qh[d + 3] * (double)w4.w;
    }
    qt[((long)b * H_ + h) * L_ + l] = (float)acc;
  }
  if (t < DH_) red[t] = (double)qh[t] * (double)bkvu[h * DH_ + t];
  __syncthreads();
  if (t == 0) {
    double s = 0.0;
    for (int i = 0; i < DH_; ++i) s += red[i];
    blog[b * H_ + h] = (float)s;
  }
}

// logits[b,h,k] over SLOTS entries via rowmapExt  (f64)
__global__ __launch_bounds__(256) void logits_kernel(
    const float* __restrict__ Kd, const int* __restrict__ rowmapExt,
    const float* __restrict__ qt, const float* __restrict__ blog,
    float* __restrict__ logits) {
  const int b = blockIdx.y;
  const int k = blockIdx.x * 16 + (threadIdx.x >> 4);
  const int h = threadIdx.x & 15;
  const float* kr = Kd + (long)rowmapExt[b * SLOTS + k] * L_;
  const float* qr = qt + ((long)b * H_ + h) * L_;
  double acc = 0.0;
  for (int l = 0; l < L_; l += 4) {
    float4 kv = *(const float4*)(kr + l);
    acc += (double)qr[l] * (double)kv.x + (double)qr[l + 1] * (double)kv.y
         + (double)qr[l + 2] * (double)kv.z + (double)qr[l + 3] * (double)kv.w;
  }
  logits[((long)b * H_ + h) * SLOTS + k] =
      (float)((acc + (double)blog[b * H_ + h]) * 0.088388347648318447);
}

// softmax over SLOTS with per-slot multipliers (hedged rows 0.5, pads 0)
__global__ __launch_bounds__(256) void softmax_kernel(
    float* __restrict__ logits, const float* __restrict__ multExt) {
  __shared__ double red[256];
  __shared__ float redf[256];
  const int bh = blockIdx.x;
  const int b = bh >> 4;
  float* row = logits + (long)bh * SLOTS;
  const float* mult = multExt + b * SLOTS;
  const int t = threadIdx.x;
  float m = -3.4e38f;
  for (int i = t; i < SLOTS; i += 256) m = fmaxf(m, row[i]);
  redf[t] = m; __syncthreads();
  for (int off = 128; off > 0; off >>= 1) {
    if (t < off) redf[t] = fmaxf(redf[t], redf[t + off]);
    __syncthreads();
  }
  m = redf[0]; __syncthreads();
  double s = 0.0;
  for (int i = t; i < SLOTS; i += 256)
    s += (double)mult[i] * exp((double)(row[i] - m));
  red[t] = s; __syncthreads();
  for (int off = 128; off > 0; off >>= 1) {
    if (t < off) red[t] += red[t + off];
    __syncthreads();
  }
  const double inv = 1.0 / red[0];
  __syncthreads();
  for (int i = t; i < SLOTS; i += 256)
    row[i] = (float)((double)mult[i] * exp((double)(row[i] - m)) * inv);
}

// vt[b,h,l] = sum_k attn[b,h,k] * Vsel[b,k,l]  over SLOTS (f32)
__global__ __launch_bounds__(256) void vt_kernel(
    const float* __restrict__ Vsel, const float* __restrict__ attn,
    float* __restrict__ vt) {
  const int b = blockIdx.y;
  const int l = blockIdx.x * 64 + (threadIdx.x & 63);
  const int hg = threadIdx.x >> 6;
  float acc[4] = {0.f, 0.f, 0.f, 0.f};
  const float* ar = attn + (long)b * H_ * SLOTS;
#pragma unroll 4
  for (int k = 0; k < SLOTS; ++k) {
    float v = Vsel[((long)b * SLOTS + k) * L_ + l];
#pragma unroll
    for (int a = 0; a < 4; ++a)
      acc[a] = fmaf(ar[(hg * 4 + a) * SLOTS + k], v, acc[a]);
  }
#pragma unroll
  for (int a = 0; a < 4; ++a)
    vt[((long)b * H_ + hg * 4 + a) * L_ + l] = acc[a];
}

// o[b,h*128+d] = vt[b,h,:] . Wv_up[:,h*128+d] + bv_up[h*128+d]  (f64)
__global__ __launch_bounds__(128) void oproj_kernel(
    const float* __restrict__ vt, const float* __restrict__ Wkvu,
    const float* __restrict__ bkvu, float* __restrict__ o) {
  __shared__ float vs[L_];
  const int h = blockIdx.x, b = blockIdx.y, t = threadIdx.x;
  for (int i = t; i < L_ / 4; i += 128)
    ((float4*)vs)[i] = ((const float4*)(vt + ((long)b * H_ + h) * L_))[i];
  __syncthreads();
  const int col = h * DH_ + t;
  double acc = 0.0;
  for (int l = 0; l < L_; ++l)
    acc += (double)vs[l] * (double)Wkvu[(long)l * 4096 + 2048 + col];
  o[b * D_ + col] = (float)(acc + (double)bkvu[2048 + col]);
}

// out[b,n] = o[b,:] @ Wout[:,n] + bout[n]  (f64)
__global__ __launch_bounds__(128) void out_kernel(
    const float* __restrict__ o, const float* __restrict__ Wout,
    const float* __restrict__ bout, float* __restrict__ out) {
  __shared__ float os[D_];
  const int b = blockIdx.y, t = threadIdx.x;
  for (int i = t; i < D_ / 4; i += 128)
    ((float4*)os)[i] = ((const float4*)(o + (long)b * D_))[i];
  __syncthreads();
  const int n = blockIdx.x * 128 + t;
  double acc = 0.0;
  for (int d = 0; d < D_; ++d) acc += (double)os[d] * (double)Wout[(long)d * D_ + n];
  out[b * D_ + n] = (float)(acc + (double)bout[n]);
}

extern "C" void kernel_launch(void* const* d_in, const int* in_sizes, int n_in,
                              void* d_out, int out_size, void* d_ws, size_t ws_size,
                              hipStream_t stream) {
  const float* x    = (const float*)d_in[0];
  const float* Wq   = (const float*)d_in[1];
  const float* bq   = (const float*)d_in[2];
  const float* Wkvd = (const float*)d_in[3];
  const float* bkvd = (const float*)d_in[4];
  const float* Wqd  = (const float*)d_in[5];
  const float* bqd  = (const float*)d_in[6];
  const float* Wkvu = (const float*)d_in[7];
  const float* bkvu = (const float*)d_in[8];
  const float* Wo   = (const float*)d_in[9];
  const float* bo   = (const float*)d_in[10];
  float* out = (float*)d_out;

  char* p = (char*)d_ws;
  auto alloc = [&](size_t bytes) {
    char* r = p;
    p += (bytes + 255) & ~(size_t)255;
    return r;
  };
  float*  Kd       = (float*)alloc((size_t)B_ * S_ * L_ * 4);       // 134.2 MB
  ushort* Kq8      = (ushort*)alloc((size_t)B_ * S_ * L_ * 2);      // 67.1 MB
  float*  Vsel     = (float*)alloc((size_t)B_ * SLOTS * L_ * 4);    // 34.6 MB
  ushort* Wsp      = (ushort*)alloc((size_t)3 * 64 * 4 * 1024 * 8 * 2);  // 12.6 MB
  float*  scores   = (float*)alloc((size_t)B_ * S_ * 4);
  float*  qidx     = (float*)alloc((size_t)B_ * L_ * 4);
  int*    rowmap   = (int*)alloc((size_t)B_ * TOPK_ * 4);
  int*    rowmapE  = (int*)alloc((size_t)B_ * SLOTS * 4);
  float*  multE    = (float*)alloc((size_t)B_ * SLOTS * 4);
  float*  vstarF   = (float*)alloc((size_t)B_ * 4);
  int2*   riskyL   = (int2*)alloc((size_t)RCAP * 8);                // 1 MB
  int*    riskyCnt = (int*)alloc(256);
  int*    flagArr  = (int*)alloc((size_t)B_ * S_ * 4);              // 0.26 MB
  int*    extraR   = (int*)alloc((size_t)B_ * EXTCAP * 4);
  int*    extraCnt = (int*)alloc((size_t)B_ * 4);
  int*    cntI2O   = (int*)alloc((size_t)B_ * 4);
  float*  qv       = (float*)alloc((size_t)B_ * D_ * 4);
  float*  qt       = (float*)alloc((size_t)B_ * H_ * L_ * 4);
  float*  blog     = (float*)alloc((size_t)B_ * H_ * 4);
  float*  logits   = (float*)alloc((size_t)B_ * H_ * SLOTS * 4);
  float*  vt       = (float*)alloc((size_t)B_ * H_ * L_ * 4);
  float*  ov       = (float*)alloc((size_t)B_ * D_ * 4);
  (void)ws_size; (void)in_sizes; (void)n_in; (void)out_size;

  zero_kernel<<<(B_ * S_ + 255) / 256, 256, 0, stream>>>(flagArr, riskyCnt, extraCnt, cntI2O);
  // one-shot: pre-split Wkv_down (both halves) into MFMA-ready bf16 planes
  wsplit_kernel<<<dim3(4, 64), 256, 0, stream>>>(Wkvd, Wsp);
  // K_down = x @ Wkv_down[:, :512] + bkv_down[:512] via bf16-split MFMA;
  // Kq8 = e4m3(K_down) from the f32 value + risky midpoint records.
  gemm_mfma<true><<<dim3(4, (B_ * S_) / 128), 256, 0, stream>>>(
      x, Wsp, 0, bkvd, Kd, Kq8, nullptr, riskyL, riskyCnt);
  qidx_kernel<<<dim3(L_ / 128, B_), 128, 0, stream>>>(x, Wqd, bqd, qidx);
  scores_kernel<<<(B_ * S_) / 4, 256, 0, stream>>>(Kq8, qidx, scores);
  topk_kernel<<<B_, 256, 0, stream>>>(scores, rowmap, vstarF);
  // hedge: find disputed rows + counterparties, build extended rowmap/mults
  risky_eval<<<RCAP / 256, 256, 0, stream>>>(riskyL, riskyCnt, Kq8, qidx, scores, vstarF,
                                             flagArr, extraR, extraCnt, cntI2O);
  counterparty_kernel<<<B_, 256, 0, stream>>>(scores, rowmap, vstarF, flagArr, extraR, extraCnt, cntI2O);
  buildext_kernel<<<dim3((SLOTS + 255) / 256, B_), 256, 0, stream>>>(rowmap, extraR, extraCnt, flagArr, rowmapE, multE);
  // V_down at selected+hedged rows via MFMA (cols 512..1023 of Wkv_down)
  gemm_mfma<false><<<dim3(4, (B_ * SLOTS) / 128), 256, 0, stream>>>(
      x, Wsp, 512, bkvd + 512, Vsel, nullptr, rowmapE, nullptr, nullptr);
  // attention (up-projections folded)
  qproj_kernel<<<dim3(D_ / 128, B_), 128, 0, stream>>>(x, Wq, bq, qv);
  qt_kernel<<<dim3(H_, B_), 256, 0, stream>>>(qv, Wkvu, bkvu, qt, blog);
  logits_kernel<<<dim3(SLOTS / 16, B_), 256, 0, stream>>>(Kd, rowmapE, qt, blog, logits);
  softmax_kernel<<<B_ * H_, 256, 0, stream>>>(logits, multE);
  vt_kernel<<<dim3(L_ / 64, B_), 256, 0, stream>>>(Vsel, logits, vt);
  oproj_kernel<<<dim3(H_, B_), 128, 0, stream>>>(vt, Wkvu, bkvu, ov);
  out_kernel<<<dim3(D_ / 128, B_), 128, 0, stream>>>(ov, Wo, bo, out);
}

// Round 11
// 2649.707 us; speedup vs baseline: 2.5226x; 1.2933x over previous
//
#include <hip/hip_runtime.h>
#include <hip/hip_bf16.h>
#include <math.h>

#define B_ 8
#define S_ 8192
#define D_ 2048
#define L_ 512
#define H_ 16
#define DH_ 128
#define TOPK_ 2048
#define EXTCAP 24
#define SLOTS (TOPK_ + 64)     // 2112, multiple of 64 and 16
#define RCAP 131072
#define DELTA 6e-6f

typedef __attribute__((ext_vector_type(8))) short short8;
typedef __attribute__((ext_vector_type(4))) float f32x4;

// fp8 e4m3fn RNE quantize from float (matches ml_dtypes astype from f32)
__device__ __forceinline__ float q8(float x) {
  float ax = fabsf(x);
  if (!(ax >= 0.015625f)) return rintf(x * 512.0f) * 0.001953125f;
  int ee; frexpf(ax, &ee);
  float step = ldexpf(1.0f, ee - 4);
  return rintf(ldexpf(x, 4 - ee)) * step;
}

// e4m3 quantize from float + midpoint analysis (for hedge detection)
__device__ __forceinline__ float q8_midf(float v, float* qflip, float* dist) {
  float av = fabsf(v);
  float step, u;
  if (!(av >= 0.015625f)) { step = 0.001953125f; u = v * 512.0f; }
  else { int ee; frexpf(av, &ee); step = ldexpf(1.0f, ee - 4); u = ldexpf(v, 4 - ee); }
  float m = rintf(u);
  float f = u - m;
  *dist = (0.5f - fabsf(f)) * step;
  float sgn = (f >= 0.0f) ? 1.0f : -1.0f;
  *qflip = (m + sgn) * step;
  return m * step;
}

__device__ __forceinline__ float b2f(unsigned u) {
  return __uint_as_float(u << 16);        // bf16 bits -> f32 (exact)
}

// f32 -> bf16 RNE bits
__device__ __forceinline__ ushort bfr(float x) {
  unsigned u = __float_as_uint(x);
  return (ushort)((u + 0x7FFFu + ((u >> 16) & 1u)) >> 16);
}
__device__ __forceinline__ float uf(ushort h) {
  return __uint_as_float(((unsigned)h) << 16);
}
// 3-way bf16 split: x ~= hi + mid + lo, residual <= 2^-24 |x|
__device__ __forceinline__ void split3(float x, ushort& h, ushort& m, ushort& l) {
  h = bfr(x); float r = x - uf(h);
  m = bfr(r); float r2 = r - uf(m);
  l = bfr(r2);
}

__device__ __forceinline__ f32x4 mfma16(short8 a, short8 b, f32x4 c) {
  return __builtin_amdgcn_mfma_f32_16x16x32_bf16(a, b, c, 0, 0, 0);
}

#if __has_builtin(__builtin_amdgcn_global_load_lds)
#define HAS_GLL 1
__device__ __forceinline__ void gload_lds16(const void* g, void* l) {
  __builtin_amdgcn_global_load_lds(
      (const __attribute__((address_space(1))) void*)g,
      (__attribute__((address_space(3))) void*)l, 16, 0, 0);
}
#else
#define HAS_GLL 0
#endif

__global__ __launch_bounds__(256) void zero_kernel(
    int* flag, int* riskyCnt, int* extraCnt, int* cntI2O) {
  int i = blockIdx.x * 256 + threadIdx.x;
  if (i < B_ * S_) flag[i] = 0;
  if (i == 0) *riskyCnt = 0;
  if (i < B_) { extraCnt[i] = 0; cntI2O[i] = 0; }
}

// Pre-split Wkv_down (2048 x 1024 f32) into 3 bf16 planes in the GEMM's
// LDS-ready layout: Wsp[T][kblk(64)][kb(4)][col(1024)][8 elems].
__global__ __launch_bounds__(256) void wsplit_kernel(
    const float* __restrict__ W, ushort* __restrict__ Wsp) {
  const int c = blockIdx.x * 256 + threadIdx.x;   // col 0..1023
  const int kblk = blockIdx.y;                    // 0..63
  float xe[32];
#pragma unroll
  for (int e = 0; e < 32; ++e) xe[e] = W[(long)(kblk * 32 + e) * 1024 + c];
#pragma unroll
  for (int kb = 0; kb < 4; ++kb) {
    ushort Hh[8], Mm[8], Ll[8];
#pragma unroll
    for (int e = 0; e < 8; ++e) split3(xe[kb * 8 + e], Hh[e], Mm[e], Ll[e]);
    *(short8*)&Wsp[((((long)0 * 64 + kblk) * 4 + kb) * 1024 + c) * 8] = *(short8*)Hh;
    *(short8*)&Wsp[((((long)1 * 64 + kblk) * 4 + kb) * 1024 + c) * 8] = *(short8*)Mm;
    *(short8*)&Wsp[((((long)2 * 64 + kblk) * 4 + kb) * 1024 + c) * 8] = *(short8*)Ll;
  }
}

#define AS_IDX(T, kb, r) ((((T)*4 + (kb)) * 128 + (r)) * 8)
#define BS_IDX(T, kb, n) ((((T)*4 + (kb)) * 128 + (n)) * 8)

// MFMA GEMM via 3-way bf16 split (6 product terms), fp32 accumulate.
// C[m, n0..n0+127] = X[row(m), :2048] @ W[:, colbase+n] + bias[n]  (f32)
// 128x128 tile (wave tile 64x64), mbase allows grid splitting (bit-identical).
template <bool QUANT>
__global__ __launch_bounds__(256, 2) void gemm_mfma(
    const float* __restrict__ X, const ushort* __restrict__ Wsp, int colbase,
    int mbase, const float* __restrict__ bias, float* __restrict__ C,
    ushort* __restrict__ Cq8, const int* __restrict__ rowmap,
    int2* __restrict__ riskyList, int* __restrict__ riskyCnt) {
  __shared__ __align__(16) ushort As[3 * 4 * 128 * 8];   // 24 KB
  __shared__ __align__(16) ushort Bs[3 * 4 * 128 * 8];   // 24 KB
  const int tid = threadIdx.x;
  const int m0 = (mbase + blockIdx.y) * 128;
  const int n0 = blockIdx.x * 128;
  // A staging assignment: 2 threads/row, 16 k each
  const int ar_ = tid >> 1;
  const int kh = (tid & 1) << 4;
  const int arow = rowmap ? rowmap[m0 + ar_] : (m0 + ar_);
  const float* aptr = X + (long)arow * D_ + kh;
  const int cb = colbase + n0;        // global col of this block's col 0

  f32x4 acc[4][4];
#pragma unroll
  for (int i = 0; i < 4; ++i)
#pragma unroll
    for (int j = 0; j < 4; ++j) acc[i][j] = (f32x4){0.f, 0.f, 0.f, 0.f};

  const int w = tid >> 6, lane = tid & 63;
  const int wm = (w & 1) * 64, wn = (w >> 1) * 64;
  const int lr = lane & 15, lq = lane >> 4;

  // A prefetch for k0 = 0
  float4 v0 = *(const float4*)(aptr + 0);
  float4 v1 = *(const float4*)(aptr + 4);
  float4 v2 = *(const float4*)(aptr + 8);
  float4 v3 = *(const float4*)(aptr + 12);

  for (int k0 = 0; k0 < D_; k0 += 32) {
    const int kblk = k0 >> 5;

    __syncthreads();   // previous iteration's LDS reads complete

    // B: pre-split planes -> LDS. 12 slices (T,kb) x 128 cols x 16B = 24KB;
    // 24 x 1KB wave-chunks; wave w loads chunks w*6..w*6+5.
#pragma unroll
    for (int i = 0; i < 6; ++i) {
      const int c = w * 6 + i;          // 0..23
      const int s = c >> 1, half = c & 1;
      const int T = s >> 2, kb = s & 3;
      const ushort* g = Wsp + ((((long)T * 64 + kblk) * 4 + kb) * 1024 +
                               (long)cb + half * 64 + lane) * 8;
#if HAS_GLL
      gload_lds16(g, &Bs[(s * 128 + half * 64) * 8]);
#else
      *(short8*)&Bs[(s * 128 + half * 64 + lane) * 8] = *(const short8*)g;
#endif
    }

    // A: split current regs & write (row ar_, k = kh..kh+15 -> 2 kb groups)
    {
      float xe[16] = {v0.x, v0.y, v0.z, v0.w, v1.x, v1.y, v1.z, v1.w,
                      v2.x, v2.y, v2.z, v2.w, v3.x, v3.y, v3.z, v3.w};
      const int kb0 = (tid & 1) * 2;
#pragma unroll
      for (int j8 = 0; j8 < 2; ++j8) {
        ushort Hh[8], Mm[8], Ll[8];
#pragma unroll
        for (int e = 0; e < 8; ++e) split3(xe[j8 * 8 + e], Hh[e], Mm[e], Ll[e]);
        *(short8*)&As[AS_IDX(0, kb0 + j8, ar_)] = *(short8*)Hh;
        *(short8*)&As[AS_IDX(1, kb0 + j8, ar_)] = *(short8*)Mm;
        *(short8*)&As[AS_IDX(2, kb0 + j8, ar_)] = *(short8*)Ll;
      }
    }
    // A prefetch for next iteration (issued before barrier)
    if (k0 + 32 < D_) {
      v0 = *(const float4*)(aptr + k0 + 32);
      v1 = *(const float4*)(aptr + k0 + 36);
      v2 = *(const float4*)(aptr + k0 + 40);
      v3 = *(const float4*)(aptr + k0 + 44);
    }
    __syncthreads();   // drains ds_writes AND global_load_lds

    // MFMA: A frags (4 m-frags x 3 terms), loop n-frags
    short8 af[4][3];
#pragma unroll
    for (int mf = 0; mf < 4; ++mf)
#pragma unroll
      for (int T = 0; T < 3; ++T)
        af[mf][T] = *(const short8*)&As[AS_IDX(T, lq, wm + mf * 16 + lr)];
#pragma unroll
    for (int nf = 0; nf < 4; ++nf) {
      short8 bh = *(const short8*)&Bs[BS_IDX(0, lq, wn + nf * 16 + lr)];
      short8 bm = *(const short8*)&Bs[BS_IDX(1, lq, wn + nf * 16 + lr)];
      short8 bl = *(const short8*)&Bs[BS_IDX(2, lq, wn + nf * 16 + lr)];
#pragma unroll
      for (int mf = 0; mf < 4; ++mf) {
        f32x4 c = acc[mf][nf];
        c = mfma16(af[mf][0], bh, c);   // hh
        c = mfma16(af[mf][0], bm, c);   // hm
        c = mfma16(af[mf][1], bh, c);   // mh
        c = mfma16(af[mf][0], bl, c);   // hl
        c = mfma16(af[mf][2], bh, c);   // lh
        c = mfma16(af[mf][1], bm, c);   // mm
        acc[mf][nf] = c;
      }
    }
  }

  // epilogue: D layout col = lane&15, row = (lane>>4)*4 + i  [m89-verified]
#pragma unroll
  for (int nf = 0; nf < 4; ++nf) {
    const int ng = n0 + wn + nf * 16 + lr;
    const float bb = bias[ng];
#pragma unroll
    for (int mf = 0; mf < 4; ++mf) {
      const int mg = m0 + wm + mf * 16 + lq * 4;
#pragma unroll
      for (int i = 0; i < 4; ++i) {
        float v = acc[mf][nf][i] + bb;
        const long crow = (long)(mg + i);
        C[crow * L_ + ng] = v;
        if (QUANT) {
          float qflip, dist;
          float q = q8_midf(v, &qflip, &dist);
          Cq8[crow * L_ + ng] = (ushort)(__float_as_uint(q) >> 16);
          if (dist < DELTA) {
            int idx = atomicAdd(riskyCnt, 1);
            if (idx < RCAP) {
              unsigned qbits = __float_as_uint(qflip) >> 16;
              riskyList[idx] = make_int2((int)crow, (ng << 16) | (int)qbits);
            }
          }
        }
      }
    }
  }
}

// q_idx[b,l] = sum_d q8(x[b,-1,d]) * q8(Wq_down[d,l]) + q8(bq_down[l])  (f64)
// SELECTION PATH — unchanged (bit-identical to passing rounds).
__global__ __launch_bounds__(128) void qidx_kernel(
    const float* __restrict__ x, const float* __restrict__ Wqd,
    const float* __restrict__ bqd, float* __restrict__ qidx) {
  __shared__ float qs[D_];
  const int b = blockIdx.y;
  const int t = threadIdx.x;
  const float* xr = x + ((long)b * S_ + (S_ - 1)) * D_;
  for (int i = t; i < D_ / 4; i += 128) {
    float4 v = ((const float4*)xr)[i];
    qs[i * 4 + 0] = q8(v.x); qs[i * 4 + 1] = q8(v.y);
    qs[i * 4 + 2] = q8(v.z); qs[i * 4 + 3] = q8(v.w);
  }
  __syncthreads();
  const int l = blockIdx.x * 128 + t;
  double acc = 0.0;
  for (int d = 0; d < D_; ++d)
    acc += (double)qs[d] * (double)q8(Wqd[(long)d * L_ + l]);
  qidx[b * L_ + l] = (float)(acc + (double)q8(bqd[l]));
}

// scores[b,s] = relu( sum_l qidx[b,l] * Kq8[b,s,l] )  (f32, wave per row)
__global__ __launch_bounds__(256) void scores_kernel(
    const ushort* __restrict__ Kq8, const float* __restrict__ qidx,
    float* __restrict__ scores) {
  __shared__ float qs[L_];
  const int m0 = blockIdx.x * 4;
  const int b = m0 >> 13;
  const int t = threadIdx.x;
  if (t < 128) ((float4*)qs)[t] = ((const float4*)(qidx + b * L_))[t];
  __syncthreads();
  const int wave = t >> 6, lane = t & 63;
  const long m = m0 + wave;
  uint4 rv = *(const uint4*)(Kq8 + m * L_ + lane * 8);
  const float* q = qs + lane * 8;
  float p = 0.f;
  p = fmaf(q[0], b2f(rv.x & 0xffffu), p);
  p = fmaf(q[1], b2f(rv.x >> 16), p);
  p = fmaf(q[2], b2f(rv.y & 0xffffu), p);
  p = fmaf(q[3], b2f(rv.y >> 16), p);
  p = fmaf(q[4], b2f(rv.z & 0xffffu), p);
  p = fmaf(q[5], b2f(rv.z >> 16), p);
  p = fmaf(q[6], b2f(rv.w & 0xffffu), p);
  p = fmaf(q[7], b2f(rv.w >> 16), p);
#pragma unroll
  for (int off = 32; off >= 1; off >>= 1) p += __shfl_xor(p, off, 64);
  if (lane == 0) scores[m] = (p > 0.f) ? p : 0.f;   // force +0
}

// deterministic top-k per batch; emits vstar; tie-pad fully parallel
__global__ __launch_bounds__(256) void topk_kernel(
    const float* __restrict__ scores, int* __restrict__ rowmap,
    float* __restrict__ vstarF) {
  __shared__ unsigned su[S_];
  __shared__ int red[256];
  __shared__ int cgt_sh;
  const int b = blockIdx.x, t = threadIdx.x;
  for (int i = t; i < S_; i += 256) su[i] = __float_as_uint(scores[(long)b * S_ + i]);
  __syncthreads();
  unsigned prefix = 0u;
  for (int bit = 30; bit >= 0; --bit) {
    unsigned cand = prefix | (1u << bit);
    int c = 0;
    for (int i = t; i < S_; i += 256) c += (su[i] >= cand) ? 1 : 0;
    red[t] = c;
    __syncthreads();
    for (int off = 128; off > 0; off >>= 1) {
      if (t < off) red[t] += red[t + off];
      __syncthreads();
    }
    if (red[0] >= TOPK_) prefix = cand;
    __syncthreads();
  }
  const unsigned vstar = prefix;
  if (t == 0) vstarF[b] = __uint_as_float(vstar);
  // compaction of (> vstar), deterministic index order
  const int c0 = t * 32;
  int cnt = 0;
  for (int i = 0; i < 32; ++i) cnt += (su[c0 + i] > vstar) ? 1 : 0;
  red[t] = cnt;
  __syncthreads();
  if (t == 0) {
    int run = 0;
    for (int i = 0; i < 256; ++i) { int c = red[i]; red[i] = run; run += c; }
    cgt_sh = run;
  }
  __syncthreads();
  int pos = red[t];
  for (int i = 0; i < 32; ++i)
    if (su[c0 + i] > vstar) rowmap[b * TOPK_ + pos++] = b * S_ + c0 + i;
  __syncthreads();
  // parallel tie-pad (== vstar), ascending index, capped at TOPK_
  int tcnt = 0;
  for (int i = 0; i < 32; ++i) tcnt += (su[c0 + i] == vstar) ? 1 : 0;
  red[t] = tcnt;
  __syncthreads();
  if (t == 0) {
    int run = 0;
    for (int i = 0; i < 256; ++i) { int c = red[i]; red[i] = run; run += c; }
  }
  __syncthreads();
  int tpos = cgt_sh + red[t];
  for (int i = 0; i < 32; ++i)
    if (su[c0 + i] == vstar) {
      if (tpos < TOPK_) rowmap[b * TOPK_ + tpos] = b * S_ + c0 + i;
      ++tpos;
    }
}

// For each risky cell: does flipping it change its row's IN/OUT status?
__global__ __launch_bounds__(256) void risky_eval(
    const int2* __restrict__ list, const int* __restrict__ riskyCnt,
    const ushort* __restrict__ Kq8, const float* __restrict__ qidx,
    const float* __restrict__ scores, const float* __restrict__ vstarF,
    int* __restrict__ flag, int* __restrict__ extraRows,
    int* __restrict__ extraCnt, int* __restrict__ cntI2O) {
  int i = blockIdx.x * 256 + threadIdx.x;
  int n = min(*riskyCnt, RCAP);
  if (i >= n) return;
  int row = list[i].x;
  int l = list[i].y >> 16;
  float qflip = b2f((unsigned)(list[i].y & 0xffff));
  int b = row >> 13;
  float qorig = b2f((unsigned)Kq8[(long)row * L_ + l]);
  float shift = qidx[b * L_ + l] * (qflip - qorig);
  float s = scores[row];
  float vs = vstarF[b];
  bool in0 = (s >= vs);
  bool in1 = (s + shift >= vs);
  if (in0 != in1) {
    if (atomicCAS(&flag[row], 0, 1) == 0) {       // claim once per row
      if (in0) {
        atomicAdd(&cntI2O[b], 1);                 // IN row at risk of dropping
      } else {
        int e = atomicAdd(&extraCnt[b], 1);       // OUT row at risk of entering
        if (e < EXTCAP) extraRows[b * EXTCAP + e] = row;
      }
    }
  }
}

// Per batch: hedge counterparties — nA min-score IN rows, nD max-score OUT rows
__global__ __launch_bounds__(256) void counterparty_kernel(
    const float* __restrict__ scores, const int* __restrict__ rowmap,
    const float* __restrict__ vstarF, int* __restrict__ flag,
    int* __restrict__ extraRows, int* __restrict__ extraCnt,
    const int* __restrict__ cntI2O) {
  __shared__ float bv[256];
  __shared__ int bi[256];
  const int b = blockIdx.x, t = threadIdx.x;
  const float vs = vstarF[b];
  const int nA = min(extraCnt[b], EXTCAP);
  const int nD = min(cntI2O[b], EXTCAP);
  for (int pass = 0; pass < nA; ++pass) {
    float best = 3.4e38f; int besti = -1;
    for (int k = t; k < TOPK_; k += 256) {
      int r = rowmap[b * TOPK_ + k];
      if (!flag[r]) { float s = scores[r]; if (s < best) { best = s; besti = r; } }
    }
    bv[t] = best; bi[t] = besti; __syncthreads();
    for (int off = 128; off > 0; off >>= 1) {
      if (t < off && bv[t + off] < bv[t]) { bv[t] = bv[t + off]; bi[t] = bi[t + off]; }
      __syncthreads();
    }
    if (t == 0 && bi[0] >= 0) flag[bi[0]] = 1;
    __syncthreads();
  }
  for (int pass = 0; pass < nD; ++pass) {
    float best = -3.4e38f; int besti = -1;
    for (int s0 = t; s0 < S_; s0 += 256) {
      int r = b * S_ + s0;
      float s = scores[r];
      if (s < vs && !flag[r] && s > best) { best = s; besti = r; }
    }
    bv[t] = best; bi[t] = besti; __syncthreads();
    for (int off = 128; off > 0; off >>= 1) {
      if (t < off && bv[t + off] > bv[t]) { bv[t] = bv[t + off]; bi[t] = bi[t + off]; }
      __syncthreads();
    }
    if (t == 0 && bi[0] >= 0) {
      flag[bi[0]] = 1;
      int e = extraCnt[b];
      if (e < EXTCAP) { extraRows[b * EXTCAP + e] = bi[0]; extraCnt[b] = e + 1; }
    }
    __syncthreads();
  }
}

// rowmapExt[b][SLOTS] = rowmap(2048) + extras + pads; multExt = 1/0.5/0
__global__ __launch_bounds__(256) void buildext_kernel(
    const int* __restrict__ rowmap, const int* __restrict__ extraRows,
    const int* __restrict__ extraCnt, const int* __restrict__ flag,
    int* __restrict__ rowmapExt, float* __restrict__ multExt) {
  const int b = blockIdx.y;
  const int k = blockIdx.x * 256 + threadIdx.x;
  if (k >= SLOTS) return;
  const int tot = min(extraCnt[b], EXTCAP);
  int row; float m;
  if (k < TOPK_) { row = rowmap[b * TOPK_ + k]; m = flag[row] ? 0.5f : 1.0f; }
  else if (k - TOPK_ < tot) { row = extraRows[b * EXTCAP + (k - TOPK_)]; m = 0.5f; }
  else { row = b * S_; m = 0.0f; }
  rowmapExt[b * SLOTS + k] = row;
  multExt[b * SLOTS + k] = m;
}

// q[b,:] = x[b,-1,:] @ Wq + bq  (f32, value path)
__global__ __launch_bounds__(128) void qproj_kernel(
    const float* __restrict__ x, const float* __restrict__ Wq,
    const float* __restrict__ bq, float* __restrict__ q) {
  __shared__ float xs[D_];
  const int b = blockIdx.y, t = threadIdx.x;
  const float* xr = x + ((long)b * S_ + (S_ - 1)) * D_;
  for (int i = t; i < D_ / 4; i += 128) ((float4*)xs)[i] = ((const float4*)xr)[i];
  __syncthreads();
  const int n = blockIdx.x * 128 + t;
  float acc = 0.f;
  for (int d = 0; d < D_; ++d) acc = fmaf(xs[d], Wq[(long)d * D_ + n], acc);
  q[b * D_ + n] = acc + bq[n];
}

// qt[b,h,l] = sum_d q[b,h*128+d] * Wk_up[l,h*128+d];  blog[b,h] = q_h . bk_up_h
__global__ __launch_bounds__(256) void qt_kernel(
    const float* __restrict__ q, const float* __restrict__ Wkvu,
    const float* __restrict__ bkvu, float* __restrict__ qt,
    float* __restrict__ blog) {
  __shared__ float qh[DH_];
  __shared__ float red[DH_];
  const int h = blockIdx.x, b = blockIdx.y, t = threadIdx.x;
  if (t < DH_) qh[t] = q[b * D_ + h * DH_ + t];
  __syncthreads();
  for (int l = t; l < L_; l += 256) {
    const float* wr = Wkvu + (long)l * 4096 + h * DH_;
    float acc = 0.f;
    for (int d = 0; d < DH_; d += 4) {
      float4 w4 = *(const float4*)(wr + d);
      acc = fmaf(qh[d], w4.x, acc);
      acc = fmaf(qh[d + 1], w4.y, acc);
      acc = fmaf(qh[d + 2], w4.z, acc);
      acc = fmaf(qh[d + 3], w4.w, acc);
    }
    qt[((long)b * H_ + h) * L_ + l] = acc;
  }
  if (t < DH_) red[t] = qh[t] * bkvu[h * DH_ + t];
  __syncthreads();
  if (t == 0) {
    float s = 0.f;
    for (int i = 0; i < DH_; ++i) s += red[i];
    blog[b * H_ + h] = s;
  }
}

// logits[b,h,k] over SLOTS entries via rowmapExt  (f32)
__global__ __launch_bounds__(256) void logits_kernel(
    const float* __restrict__ Kd, const int* __restrict__ rowmapExt,
    const float* __restrict__ qt, const float* __restrict__ blog,
    float* __restrict__ logits) {
  const int b = blockIdx.y;
  const int k = blockIdx.x * 16 + (threadIdx.x >> 4);
  const int h = threadIdx.x & 15;
  const float* kr = Kd + (long)rowmapExt[b * SLOTS + k] * L_;
  const float* qr = qt + ((long)b * H_ + h) * L_;
  float acc = 0.f;
  for (int l = 0; l < L_; l += 4) {
    float4 kv = *(const float4*)(kr + l);
    acc = fmaf(qr[l], kv.x, acc);
    acc = fmaf(qr[l + 1], kv.y, acc);
    acc = fmaf(qr[l + 2], kv.z, acc);
    acc = fmaf(qr[l + 3], kv.w, acc);
  }
  logits[((long)b * H_ + h) * SLOTS + k] =
      (acc + blog[b * H_ + h]) * 0.088388347648318447f;
}

// softmax over SLOTS with per-slot multipliers (hedged rows 0.5, pads 0)
__global__ __launch_bounds__(256) void softmax_kernel(
    float* __restrict__ logits, const float* __restrict__ multExt) {
  __shared__ double red[256];
  __shared__ float redf[256];
  const int bh = blockIdx.x;
  const int b = bh >> 4;
  float* row = logits + (long)bh * SLOTS;
  const float* mult = multExt + b * SLOTS;
  const int t = threadIdx.x;
  float m = -3.4e38f;
  for (int i = t; i < SLOTS; i += 256) m = fmaxf(m, row[i]);
  redf[t] = m; __syncthreads();
  for (int off = 128; off > 0; off >>= 1) {
    if (t < off) redf[t] = fmaxf(redf[t], redf[t + off]);
    __syncthreads();
  }
  m = redf[0]; __syncthreads();
  double s = 0.0;
  for (int i = t; i < SLOTS; i += 256)
    s += (double)mult[i] * exp((double)(row[i] - m));
  red[t] = s; __syncthreads();
  for (int off = 128; off > 0; off >>= 1) {
    if (t < off) red[t] += red[t + off];
    __syncthreads();
  }
  const double inv = 1.0 / red[0];
  __syncthreads();
  for (int i = t; i < SLOTS; i += 256)
    row[i] = (float)((double)mult[i] * exp((double)(row[i] - m)) * inv);
}

// vt[b,h,l] = sum_k attn[b,h,k] * Vsel[b,k,l]  over SLOTS (f32)
__global__ __launch_bounds__(256) void vt_kernel(
    const float* __restrict__ Vsel, const float* __restrict__ attn,
    float* __restrict__ vt) {
  const int b = blockIdx.y;
  const int l = blockIdx.x * 64 + (threadIdx.x & 63);
  const int hg = threadIdx.x >> 6;
  float acc[4] = {0.f, 0.f, 0.f, 0.f};
  const float* ar = attn + (long)b * H_ * SLOTS;
#pragma unroll 4
  for (int k = 0; k < SLOTS; ++k) {
    float v = Vsel[((long)b * SLOTS + k) * L_ + l];
#pragma unroll
    for (int a = 0; a < 4; ++a)
      acc[a] = fmaf(ar[(hg * 4 + a) * SLOTS + k], v, acc[a]);
  }
#pragma unroll
  for (int a = 0; a < 4; ++a)
    vt[((long)b * H_ + hg * 4 + a) * L_ + l] = acc[a];
}

// o[b,h*128+d] = vt[b,h,:] . Wv_up[:,h*128+d] + bv_up[h*128+d]  (f32)
__global__ __launch_bounds__(128) void oproj_kernel(
    const float* __restrict__ vt, const float* __restrict__ Wkvu,
    const float* __restrict__ bkvu, float* __restrict__ o) {
  __shared__ float vs[L_];
  const int h = blockIdx.x, b = blockIdx.y, t = threadIdx.x;
  for (int i = t; i < L_ / 4; i += 128)
    ((float4*)vs)[i] = ((const float4*)(vt + ((long)b * H_ + h) * L_))[i];
  __syncthreads();
  const int col = h * DH_ + t;
  float acc = 0.f;
  for (int l = 0; l < L_; ++l)
    acc = fmaf(vs[l], Wkvu[(long)l * 4096 + 2048 + col], acc);
  o[b * D_ + col] = acc + bkvu[2048 + col];
}

// out[b,n] = o[b,:] @ Wout[:,n] + bout[n]  (f32)
__global__ __launch_bounds__(128) void out_kernel(
    const float* __restrict__ o, const float* __restrict__ Wout,
    const float* __restrict__ bout, float* __restrict__ out) {
  __shared__ float os[D_];
  const int b = blockIdx.y, t = threadIdx.x;
  for (int i = t; i < D_ / 4; i += 128)
    ((float4*)os)[i] = ((const float4*)(o + (long)b * D_))[i];
  __syncthreads();
  const int n = blockIdx.x * 128 + t;
  float acc = 0.f;
  for (int d = 0; d < D_; ++d) acc = fmaf(os[d], Wout[(long)d * D_ + n], acc);
  out[b * D_ + n] = acc + bout[n];
}

extern "C" void kernel_launch(void* const* d_in, const int* in_sizes, int n_in,
                              void* d_out, int out_size, void* d_ws, size_t ws_size,
                              hipStream_t stream) {
  const float* x    = (const float*)d_in[0];
  const float* Wq   = (const float*)d_in[1];
  const float* bq   = (const float*)d_in[2];
  const float* Wkvd = (const float*)d_in[3];
  const float* bkvd = (const float*)d_in[4];
  const float* Wqd  = (const float*)d_in[5];
  const float* bqd  = (const float*)d_in[6];
  const float* Wkvu = (const float*)d_in[7];
  const float* bkvu = (const float*)d_in[8];
  const float* Wo   = (const float*)d_in[9];
  const float* bo   = (const float*)d_in[10];
  float* out = (float*)d_out;

  char* p = (char*)d_ws;
  auto alloc = [&](size_t bytes) {
    char* r = p;
    p += (bytes + 255) & ~(size_t)255;
    return r;
  };
  float*  Kd       = (float*)alloc((size_t)B_ * S_ * L_ * 4);       // 134.2 MB
  ushort* Kq8      = (ushort*)alloc((size_t)B_ * S_ * L_ * 2);      // 67.1 MB
  float*  Vsel     = (float*)alloc((size_t)B_ * SLOTS * L_ * 4);    // 34.6 MB
  ushort* Wsp      = (ushort*)alloc((size_t)3 * 64 * 4 * 1024 * 8 * 2);  // 12.6 MB
  float*  scores   = (float*)alloc((size_t)B_ * S_ * 4);
  float*  qidx     = (float*)alloc((size_t)B_ * L_ * 4);
  int*    rowmap   = (int*)alloc((size_t)B_ * TOPK_ * 4);
  int*    rowmapE  = (int*)alloc((size_t)B_ * SLOTS * 4);
  float*  multE    = (float*)alloc((size_t)B_ * SLOTS * 4);
  float*  vstarF   = (float*)alloc((size_t)B_ * 4);
  int2*   riskyL   = (int2*)alloc((size_t)RCAP * 8);                // 1 MB
  int*    riskyCnt = (int*)alloc(256);
  int*    flagArr  = (int*)alloc((size_t)B_ * S_ * 4);              // 0.26 MB
  int*    extraR   = (int*)alloc((size_t)B_ * EXTCAP * 4);
  int*    extraCnt = (int*)alloc((size_t)B_ * 4);
  int*    cntI2O   = (int*)alloc((size_t)B_ * 4);
  float*  qv       = (float*)alloc((size_t)B_ * D_ * 4);
  float*  qt       = (float*)alloc((size_t)B_ * H_ * L_ * 4);
  float*  blog     = (float*)alloc((size_t)B_ * H_ * 4);
  float*  logits   = (float*)alloc((size_t)B_ * H_ * SLOTS * 4);
  float*  vt       = (float*)alloc((size_t)B_ * H_ * L_ * 4);
  float*  ov       = (float*)alloc((size_t)B_ * D_ * 4);
  (void)ws_size; (void)in_sizes; (void)n_in; (void)out_size;

  zero_kernel<<<(B_ * S_ + 255) / 256, 256, 0, stream>>>(flagArr, riskyCnt, extraCnt, cntI2O);
  // one-shot: pre-split Wkv_down (both halves) into MFMA-ready bf16 planes
  wsplit_kernel<<<dim3(4, 64), 256, 0, stream>>>(Wkvd, Wsp);
  // K_down via bf16-split MFMA, split into 2 half-grid dispatches
  // (bit-identical math; drops profiler top-5 threshold for tail visibility)
  gemm_mfma<true><<<dim3(4, 256), 256, 0, stream>>>(
      x, Wsp, 0, 0, bkvd, Kd, Kq8, nullptr, riskyL, riskyCnt);
  gemm_mfma<true><<<dim3(4, 256), 256, 0, stream>>>(
      x, Wsp, 0, 256, bkvd, Kd, Kq8, nullptr, riskyL, riskyCnt);
  qidx_kernel<<<dim3(L_ / 128, B_), 128, 0, stream>>>(x, Wqd, bqd, qidx);
  scores_kernel<<<(B_ * S_) / 4, 256, 0, stream>>>(Kq8, qidx, scores);
  topk_kernel<<<B_, 256, 0, stream>>>(scores, rowmap, vstarF);
  // hedge: find disputed rows + counterparties, build extended rowmap/mults
  risky_eval<<<RCAP / 256, 256, 0, stream>>>(riskyL, riskyCnt, Kq8, qidx, scores, vstarF,
                                             flagArr, extraR, extraCnt, cntI2O);
  counterparty_kernel<<<B_, 256, 0, stream>>>(scores, rowmap, vstarF, flagArr, extraR, extraCnt, cntI2O);
  buildext_kernel<<<dim3((SLOTS + 255) / 256, B_), 256, 0, stream>>>(rowmap, extraR, extraCnt, flagArr, rowmapE, multE);
  // V_down at selected+hedged rows via MFMA (cols 512..1023 of Wkv_down)
  gemm_mfma<false><<<dim3(4, (B_ * SLOTS) / 128), 256, 0, stream>>>(
      x, Wsp, 512, 0, bkvd + 512, Vsel, nullptr, rowmapE, nullptr, nullptr);
  // attention (up-projections folded)
  qproj_kernel<<<dim3(D_ / 128, B_), 128, 0, stream>>>(x, Wq, bq, qv);
  qt_kernel<<<dim3(H_, B_), 256, 0, stream>>>(qv, Wkvu, bkvu, qt, blog);
  logits_kernel<<<dim3(SLOTS / 16, B_), 256, 0, stream>>>(Kd, rowmapE, qt, blog, logits);
  softmax_kernel<<<B_ * H_, 256, 0, stream>>>(logits, multE);
  vt_kernel<<<dim3(L_ / 64, B_), 256, 0, stream>>>(Vsel, logits, vt);
  oproj_kernel<<<dim3(H_, B_), 128, 0, stream>>>(vt, Wkvu, bkvu, ov);
  out_kernel<<<dim3(D_ / 128, B_), 128, 0, stream>>>(ov, Wo, bo, out);
}

// Round 12
// 1866.959 us; speedup vs baseline: 3.5802x; 1.4193x over previous
//
#include <hip/hip_runtime.h>
#include <hip/hip_bf16.h>
#include <math.h>

#define B_ 8
#define S_ 8192
#define D_ 2048
#define L_ 512
#define H_ 16
#define DH_ 128
#define TOPK_ 2048
#define EXTCAP 24
#define SLOTS (TOPK_ + 64)     // 2112, multiple of 64 and 16
#define RCAP 131072
#define DELTA 6e-6f
#define QCH 32                 // qidx d-chunks
#define QCHD (D_ / QCH)        // 64 d per chunk

typedef __attribute__((ext_vector_type(8))) short short8;
typedef __attribute__((ext_vector_type(4))) float f32x4;

// fp8 e4m3fn RNE quantize from float (matches ml_dtypes astype from f32)
__device__ __forceinline__ float q8(float x) {
  float ax = fabsf(x);
  if (!(ax >= 0.015625f)) return rintf(x * 512.0f) * 0.001953125f;
  int ee; frexpf(ax, &ee);
  float step = ldexpf(1.0f, ee - 4);
  return rintf(ldexpf(x, 4 - ee)) * step;
}

// e4m3 quantize from float + midpoint analysis (for hedge detection)
__device__ __forceinline__ float q8_midf(float v, float* qflip, float* dist) {
  float av = fabsf(v);
  float step, u;
  if (!(av >= 0.015625f)) { step = 0.001953125f; u = v * 512.0f; }
  else { int ee; frexpf(av, &ee); step = ldexpf(1.0f, ee - 4); u = ldexpf(v, 4 - ee); }
  float m = rintf(u);
  float f = u - m;
  *dist = (0.5f - fabsf(f)) * step;
  float sgn = (f >= 0.0f) ? 1.0f : -1.0f;
  *qflip = (m + sgn) * step;
  return m * step;
}

__device__ __forceinline__ float b2f(unsigned u) {
  return __uint_as_float(u << 16);        // bf16 bits -> f32 (exact)
}

// f32 -> bf16 RNE bits
__device__ __forceinline__ ushort bfr(float x) {
  unsigned u = __float_as_uint(x);
  return (ushort)((u + 0x7FFFu + ((u >> 16) & 1u)) >> 16);
}
__device__ __forceinline__ float uf(ushort h) {
  return __uint_as_float(((unsigned)h) << 16);
}
// 3-way bf16 split: x ~= hi + mid + lo, residual <= 2^-24 |x|
__device__ __forceinline__ void split3(float x, ushort& h, ushort& m, ushort& l) {
  h = bfr(x); float r = x - uf(h);
  m = bfr(r); float r2 = r - uf(m);
  l = bfr(r2);
}

__device__ __forceinline__ f32x4 mfma16(short8 a, short8 b, f32x4 c) {
  return __builtin_amdgcn_mfma_f32_16x16x32_bf16(a, b, c, 0, 0, 0);
}

#if __has_builtin(__builtin_amdgcn_global_load_lds)
#define HAS_GLL 1
__device__ __forceinline__ void gload_lds16(const void* g, void* l) {
  __builtin_amdgcn_global_load_lds(
      (const __attribute__((address_space(1))) void*)g,
      (__attribute__((address_space(3))) void*)l, 16, 0, 0);
}
#else
#define HAS_GLL 0
#endif

__global__ __launch_bounds__(256) void zero_kernel(
    int* flag, int* riskyCnt, int* extraCnt, int* cntI2O) {
  int i = blockIdx.x * 256 + threadIdx.x;
  if (i < B_ * S_) flag[i] = 0;
  if (i == 0) *riskyCnt = 0;
  if (i < B_) { extraCnt[i] = 0; cntI2O[i] = 0; }
}

// Pre-split Wkv_down (2048 x 1024 f32) into 3 bf16 planes in the GEMM's
// LDS-ready layout: Wsp[T][kblk(64)][kb(4)][col(1024)][8 elems].
__global__ __launch_bounds__(256) void wsplit_kernel(
    const float* __restrict__ W, ushort* __restrict__ Wsp) {
  const int c = blockIdx.x * 256 + threadIdx.x;   // col 0..1023
  const int kblk = blockIdx.y;                    // 0..63
  float xe[32];
#pragma unroll
  for (int e = 0; e < 32; ++e) xe[e] = W[(long)(kblk * 32 + e) * 1024 + c];
#pragma unroll
  for (int kb = 0; kb < 4; ++kb) {
    ushort Hh[8], Mm[8], Ll[8];
#pragma unroll
    for (int e = 0; e < 8; ++e) split3(xe[kb * 8 + e], Hh[e], Mm[e], Ll[e]);
    *(short8*)&Wsp[((((long)0 * 64 + kblk) * 4 + kb) * 1024 + c) * 8] = *(short8*)Hh;
    *(short8*)&Wsp[((((long)1 * 64 + kblk) * 4 + kb) * 1024 + c) * 8] = *(short8*)Mm;
    *(short8*)&Wsp[((((long)2 * 64 + kblk) * 4 + kb) * 1024 + c) * 8] = *(short8*)Ll;
  }
}

// One-shot: Wq8[d][l] = q8(Wq_down[d][l]) stored as bf16 bits (exact)
__global__ __launch_bounds__(256) void wq8_kernel(
    const float* __restrict__ Wqd, ushort* __restrict__ Wq8) {
  const long i = ((long)blockIdx.x * 256 + threadIdx.x) * 4;
  float4 v = *(const float4*)(Wqd + i);
  ushort4 o;
  o.x = (ushort)(__float_as_uint(q8(v.x)) >> 16);
  o.y = (ushort)(__float_as_uint(q8(v.y)) >> 16);
  o.z = (ushort)(__float_as_uint(q8(v.z)) >> 16);
  o.w = (ushort)(__float_as_uint(q8(v.w)) >> 16);
  *(ushort4*)(Wq8 + i) = o;
}

#define AS_IDX(T, kb, r) ((((T)*4 + (kb)) * 128 + (r)) * 8)
#define BS_IDX(T, kb, n) ((((T)*4 + (kb)) * 128 + (n)) * 8)

// MFMA GEMM via 3-way bf16 split (6 product terms), fp32 accumulate.
// C[m, n0..n0+127] = X[row(m), :2048] @ W[:, colbase+n] + bias[n]  (f32)
// 128x128 tile (wave tile 64x64), mbase allows grid splitting (bit-identical).
template <bool QUANT>
__global__ __launch_bounds__(256, 2) void gemm_mfma(
    const float* __restrict__ X, const ushort* __restrict__ Wsp, int colbase,
    int mbase, const float* __restrict__ bias, float* __restrict__ C,
    ushort* __restrict__ Cq8, const int* __restrict__ rowmap,
    int2* __restrict__ riskyList, int* __restrict__ riskyCnt) {
  __shared__ __align__(16) ushort As[3 * 4 * 128 * 8];   // 24 KB
  __shared__ __align__(16) ushort Bs[3 * 4 * 128 * 8];   // 24 KB
  const int tid = threadIdx.x;
  const int m0 = (mbase + blockIdx.y) * 128;
  const int n0 = blockIdx.x * 128;
  // A staging assignment: 2 threads/row, 16 k each
  const int ar_ = tid >> 1;
  const int kh = (tid & 1) << 4;
  const int arow = rowmap ? rowmap[m0 + ar_] : (m0 + ar_);
  const float* aptr = X + (long)arow * D_ + kh;
  const int cb = colbase + n0;        // global col of this block's col 0

  f32x4 acc[4][4];
#pragma unroll
  for (int i = 0; i < 4; ++i)
#pragma unroll
    for (int j = 0; j < 4; ++j) acc[i][j] = (f32x4){0.f, 0.f, 0.f, 0.f};

  const int w = tid >> 6, lane = tid & 63;
  const int wm = (w & 1) * 64, wn = (w >> 1) * 64;
  const int lr = lane & 15, lq = lane >> 4;

  // A prefetch for k0 = 0
  float4 v0 = *(const float4*)(aptr + 0);
  float4 v1 = *(const float4*)(aptr + 4);
  float4 v2 = *(const float4*)(aptr + 8);
  float4 v3 = *(const float4*)(aptr + 12);

  for (int k0 = 0; k0 < D_; k0 += 32) {
    const int kblk = k0 >> 5;

    __syncthreads();   // previous iteration's LDS reads complete

    // B: pre-split planes -> LDS. 12 slices (T,kb) x 128 cols x 16B = 24KB;
    // 24 x 1KB wave-chunks; wave w loads chunks w*6..w*6+5.
#pragma unroll
    for (int i = 0; i < 6; ++i) {
      const int c = w * 6 + i;          // 0..23
      const int s = c >> 1, half = c & 1;
      const int T = s >> 2, kb = s & 3;
      const ushort* g = Wsp + ((((long)T * 64 + kblk) * 4 + kb) * 1024 +
                               (long)cb + half * 64 + lane) * 8;
#if HAS_GLL
      gload_lds16(g, &Bs[(s * 128 + half * 64) * 8]);
#else
      *(short8*)&Bs[(s * 128 + half * 64 + lane) * 8] = *(const short8*)g;
#endif
    }

    // A: split current regs & write (row ar_, k = kh..kh+15 -> 2 kb groups)
    {
      float xe[16] = {v0.x, v0.y, v0.z, v0.w, v1.x, v1.y, v1.z, v1.w,
                      v2.x, v2.y, v2.z, v2.w, v3.x, v3.y, v3.z, v3.w};
      const int kb0 = (tid & 1) * 2;
#pragma unroll
      for (int j8 = 0; j8 < 2; ++j8) {
        ushort Hh[8], Mm[8], Ll[8];
#pragma unroll
        for (int e = 0; e < 8; ++e) split3(xe[j8 * 8 + e], Hh[e], Mm[e], Ll[e]);
        *(short8*)&As[AS_IDX(0, kb0 + j8, ar_)] = *(short8*)Hh;
        *(short8*)&As[AS_IDX(1, kb0 + j8, ar_)] = *(short8*)Mm;
        *(short8*)&As[AS_IDX(2, kb0 + j8, ar_)] = *(short8*)Ll;
      }
    }
    // A prefetch for next iteration (issued before barrier)
    if (k0 + 32 < D_) {
      v0 = *(const float4*)(aptr + k0 + 32);
      v1 = *(const float4*)(aptr + k0 + 36);
      v2 = *(const float4*)(aptr + k0 + 40);
      v3 = *(const float4*)(aptr + k0 + 44);
    }
    __syncthreads();   // drains ds_writes AND global_load_lds

    // MFMA: A frags (4 m-frags x 3 terms), loop n-frags
    short8 af[4][3];
#pragma unroll
    for (int mf = 0; mf < 4; ++mf)
#pragma unroll
      for (int T = 0; T < 3; ++T)
        af[mf][T] = *(const short8*)&As[AS_IDX(T, lq, wm + mf * 16 + lr)];
#pragma unroll
    for (int nf = 0; nf < 4; ++nf) {
      short8 bh = *(const short8*)&Bs[BS_IDX(0, lq, wn + nf * 16 + lr)];
      short8 bm = *(const short8*)&Bs[BS_IDX(1, lq, wn + nf * 16 + lr)];
      short8 bl = *(const short8*)&Bs[BS_IDX(2, lq, wn + nf * 16 + lr)];
#pragma unroll
      for (int mf = 0; mf < 4; ++mf) {
        f32x4 c = acc[mf][nf];
        c = mfma16(af[mf][0], bh, c);   // hh
        c = mfma16(af[mf][0], bm, c);   // hm
        c = mfma16(af[mf][1], bh, c);   // mh
        c = mfma16(af[mf][0], bl, c);   // hl
        c = mfma16(af[mf][2], bh, c);   // lh
        c = mfma16(af[mf][1], bm, c);   // mm
        acc[mf][nf] = c;
      }
    }
  }

  // epilogue: D layout col = lane&15, row = (lane>>4)*4 + i  [m89-verified]
#pragma unroll
  for (int nf = 0; nf < 4; ++nf) {
    const int ng = n0 + wn + nf * 16 + lr;
    const float bb = bias[ng];
#pragma unroll
    for (int mf = 0; mf < 4; ++mf) {
      const int mg = m0 + wm + mf * 16 + lq * 4;
#pragma unroll
      for (int i = 0; i < 4; ++i) {
        float v = acc[mf][nf][i] + bb;
        const long crow = (long)(mg + i);
        C[crow * L_ + ng] = v;
        if (QUANT) {
          float qflip, dist;
          float q = q8_midf(v, &qflip, &dist);
          Cq8[crow * L_ + ng] = (ushort)(__float_as_uint(q) >> 16);
          if (dist < DELTA) {
            int idx = atomicAdd(riskyCnt, 1);
            if (idx < RCAP) {
              unsigned qbits = __float_as_uint(qflip) >> 16;
              riskyList[idx] = make_int2((int)crow, (ng << 16) | (int)qbits);
            }
          }
        }
      }
    }
  }
}

// qidx partials: qpart[b][c][l] = sum_{d in chunk c} q8(x[b,-1,d]) * Wq8[d,l]
// f64 accumulation per chunk; chunks summed ascending in qidx_reduce
// (reassociation ~1e-16 rel — selection-safe vs 7e-3 boundary spacing).
__global__ __launch_bounds__(256) void qidx_part(
    const float* __restrict__ x, const ushort* __restrict__ Wq8,
    double* __restrict__ qpart) {
  __shared__ float qs[QCHD];
  const int b = blockIdx.y;
  const int c = blockIdx.x;
  const int t = threadIdx.x;
  const int d0 = c * QCHD;
  const float* xr = x + ((long)b * S_ + (S_ - 1)) * D_ + d0;
  if (t < QCHD) qs[t] = q8(xr[t]);
  __syncthreads();
  double a0 = 0.0, a1 = 0.0;
  const ushort* wr = Wq8 + (long)d0 * L_;
  for (int dd = 0; dd < QCHD; ++dd) {
    const double qv = (double)qs[dd];
    a0 += qv * (double)b2f((unsigned)wr[dd * L_ + t]);
    a1 += qv * (double)b2f((unsigned)wr[dd * L_ + t + 256]);
  }
  double* qp = qpart + ((long)b * QCH + c) * L_;
  qp[t] = a0;
  qp[t + 256] = a1;
}

__global__ __launch_bounds__(256) void qidx_reduce(
    const double* __restrict__ qpart, const float* __restrict__ bqd,
    float* __restrict__ qidx) {
  const int i = blockIdx.x * 256 + threadIdx.x;   // 0..B_*L_-1
  const int b = i >> 9, l = i & 511;
  double acc = 0.0;
  for (int c = 0; c < QCH; ++c)
    acc += qpart[((long)b * QCH + c) * L_ + l];
  qidx[i] = (float)(acc + (double)q8(bqd[l]));
}

// scores[b,s] = relu( sum_l qidx[b,l] * Kq8[b,s,l] )  (f32, wave per row)
__global__ __launch_bounds__(256) void scores_kernel(
    const ushort* __restrict__ Kq8, const float* __restrict__ qidx,
    float* __restrict__ scores) {
  __shared__ float qs[L_];
  const int m0 = blockIdx.x * 4;
  const int b = m0 >> 13;
  const int t = threadIdx.x;
  if (t < 128) ((float4*)qs)[t] = ((const float4*)(qidx + b * L_))[t];
  __syncthreads();
  const int wave = t >> 6, lane = t & 63;
  const long m = m0 + wave;
  uint4 rv = *(const uint4*)(Kq8 + m * L_ + lane * 8);
  const float* q = qs + lane * 8;
  float p = 0.f;
  p = fmaf(q[0], b2f(rv.x & 0xffffu), p);
  p = fmaf(q[1], b2f(rv.x >> 16), p);
  p = fmaf(q[2], b2f(rv.y & 0xffffu), p);
  p = fmaf(q[3], b2f(rv.y >> 16), p);
  p = fmaf(q[4], b2f(rv.z & 0xffffu), p);
  p = fmaf(q[5], b2f(rv.z >> 16), p);
  p = fmaf(q[6], b2f(rv.w & 0xffffu), p);
  p = fmaf(q[7], b2f(rv.w >> 16), p);
#pragma unroll
  for (int off = 32; off >= 1; off >>= 1) p += __shfl_xor(p, off, 64);
  if (lane == 0) scores[m] = (p > 0.f) ? p : 0.f;   // force +0
}

// deterministic top-k per batch; emits vstar; tie-pad fully parallel
__global__ __launch_bounds__(256) void topk_kernel(
    const float* __restrict__ scores, int* __restrict__ rowmap,
    float* __restrict__ vstarF) {
  __shared__ unsigned su[S_];
  __shared__ int red[256];
  __shared__ int cgt_sh;
  const int b = blockIdx.x, t = threadIdx.x;
  for (int i = t; i < S_; i += 256) su[i] = __float_as_uint(scores[(long)b * S_ + i]);
  __syncthreads();
  unsigned prefix = 0u;
  for (int bit = 30; bit >= 0; --bit) {
    unsigned cand = prefix | (1u << bit);
    int c = 0;
    for (int i = t; i < S_; i += 256) c += (su[i] >= cand) ? 1 : 0;
    red[t] = c;
    __syncthreads();
    for (int off = 128; off > 0; off >>= 1) {
      if (t < off) red[t] += red[t + off];
      __syncthreads();
    }
    if (red[0] >= TOPK_) prefix = cand;
    __syncthreads();
  }
  const unsigned vstar = prefix;
  if (t == 0) vstarF[b] = __uint_as_float(vstar);
  // compaction of (> vstar), deterministic index order
  const int c0 = t * 32;
  int cnt = 0;
  for (int i = 0; i < 32; ++i) cnt += (su[c0 + i] > vstar) ? 1 : 0;
  red[t] = cnt;
  __syncthreads();
  if (t == 0) {
    int run = 0;
    for (int i = 0; i < 256; ++i) { int c = red[i]; red[i] = run; run += c; }
    cgt_sh = run;
  }
  __syncthreads();
  int pos = red[t];
  for (int i = 0; i < 32; ++i)
    if (su[c0 + i] > vstar) rowmap[b * TOPK_ + pos++] = b * S_ + c0 + i;
  __syncthreads();
  // parallel tie-pad (== vstar), ascending index, capped at TOPK_
  int tcnt = 0;
  for (int i = 0; i < 32; ++i) tcnt += (su[c0 + i] == vstar) ? 1 : 0;
  red[t] = tcnt;
  __syncthreads();
  if (t == 0) {
    int run = 0;
    for (int i = 0; i < 256; ++i) { int c = red[i]; red[i] = run; run += c; }
  }
  __syncthreads();
  int tpos = cgt_sh + red[t];
  for (int i = 0; i < 32; ++i)
    if (su[c0 + i] == vstar) {
      if (tpos < TOPK_) rowmap[b * TOPK_ + tpos] = b * S_ + c0 + i;
      ++tpos;
    }
}

// For each risky cell: does flipping it change its row's IN/OUT status?
__global__ __launch_bounds__(256) void risky_eval(
    const int2* __restrict__ list, const int* __restrict__ riskyCnt,
    const ushort* __restrict__ Kq8, const float* __restrict__ qidx,
    const float* __restrict__ scores, const float* __restrict__ vstarF,
    int* __restrict__ flag, int* __restrict__ extraRows,
    int* __restrict__ extraCnt, int* __restrict__ cntI2O) {
  int i = blockIdx.x * 256 + threadIdx.x;
  int n = min(*riskyCnt, RCAP);
  if (i >= n) return;
  int row = list[i].x;
  int l = list[i].y >> 16;
  float qflip = b2f((unsigned)(list[i].y & 0xffff));
  int b = row >> 13;
  float qorig = b2f((unsigned)Kq8[(long)row * L_ + l]);
  float shift = qidx[b * L_ + l] * (qflip - qorig);
  float s = scores[row];
  float vs = vstarF[b];
  bool in0 = (s >= vs);
  bool in1 = (s + shift >= vs);
  if (in0 != in1) {
    if (atomicCAS(&flag[row], 0, 1) == 0) {       // claim once per row
      if (in0) {
        atomicAdd(&cntI2O[b], 1);                 // IN row at risk of dropping
      } else {
        int e = atomicAdd(&extraCnt[b], 1);       // OUT row at risk of entering
        if (e < EXTCAP) extraRows[b * EXTCAP + e] = row;
      }
    }
  }
}

// Per batch: hedge counterparties — nA min-score IN rows, nD max-score OUT rows
__global__ __launch_bounds__(256) void counterparty_kernel(
    const float* __restrict__ scores, const int* __restrict__ rowmap,
    const float* __restrict__ vstarF, int* __restrict__ flag,
    int* __restrict__ extraRows, int* __restrict__ extraCnt,
    const int* __restrict__ cntI2O) {
  __shared__ float bv[256];
  __shared__ int bi[256];
  const int b = blockIdx.x, t = threadIdx.x;
  const float vs = vstarF[b];
  const int nA = min(extraCnt[b], EXTCAP);
  const int nD = min(cntI2O[b], EXTCAP);
  for (int pass = 0; pass < nA; ++pass) {
    float best = 3.4e38f; int besti = -1;
    for (int k = t; k < TOPK_; k += 256) {
      int r = rowmap[b * TOPK_ + k];
      if (!flag[r]) { float s = scores[r]; if (s < best) { best = s; besti = r; } }
    }
    bv[t] = best; bi[t] = besti; __syncthreads();
    for (int off = 128; off > 0; off >>= 1) {
      if (t < off && bv[t + off] < bv[t]) { bv[t] = bv[t + off]; bi[t] = bi[t + off]; }
      __syncthreads();
    }
    if (t == 0 && bi[0] >= 0) flag[bi[0]] = 1;
    __syncthreads();
  }
  for (int pass = 0; pass < nD; ++pass) {
    float best = -3.4e38f; int besti = -1;
    for (int s0 = t; s0 < S_; s0 += 256) {
      int r = b * S_ + s0;
      float s = scores[r];
      if (s < vs && !flag[r] && s > best) { best = s; besti = r; }
    }
    bv[t] = best; bi[t] = besti; __syncthreads();
    for (int off = 128; off > 0; off >>= 1) {
      if (t < off && bv[t + off] > bv[t]) { bv[t] = bv[t + off]; bi[t] = bi[t + off]; }
      __syncthreads();
    }
    if (t == 0 && bi[0] >= 0) {
      flag[bi[0]] = 1;
      int e = extraCnt[b];
      if (e < EXTCAP) { extraRows[b * EXTCAP + e] = bi[0]; extraCnt[b] = e + 1; }
    }
    __syncthreads();
  }
}

// rowmapExt[b][SLOTS] = rowmap(2048) + extras + pads; multExt = 1/0.5/0
__global__ __launch_bounds__(256) void buildext_kernel(
    const int* __restrict__ rowmap, const int* __restrict__ extraRows,
    const int* __restrict__ extraCnt, const int* __restrict__ flag,
    int* __restrict__ rowmapExt, float* __restrict__ multExt) {
  const int b = blockIdx.y;
  const int k = blockIdx.x * 256 + threadIdx.x;
  if (k >= SLOTS) return;
  const int tot = min(extraCnt[b], EXTCAP);
  int row; float m;
  if (k < TOPK_) { row = rowmap[b * TOPK_ + k]; m = flag[row] ? 0.5f : 1.0f; }
  else if (k - TOPK_ < tot) { row = extraRows[b * EXTCAP + (k - TOPK_)]; m = 0.5f; }
  else { row = b * S_; m = 0.0f; }
  rowmapExt[b * SLOTS + k] = row;
  multExt[b * SLOTS + k] = m;
}

// q[b,:] = x[b,-1,:] @ Wq + bq  (f32, value path)
__global__ __launch_bounds__(128) void qproj_kernel(
    const float* __restrict__ x, const float* __restrict__ Wq,
    const float* __restrict__ bq, float* __restrict__ q) {
  __shared__ float xs[D_];
  const int b = blockIdx.y, t = threadIdx.x;
  const float* xr = x + ((long)b * S_ + (S_ - 1)) * D_;
  for (int i = t; i < D_ / 4; i += 128) ((float4*)xs)[i] = ((const float4*)xr)[i];
  __syncthreads();
  const int n = blockIdx.x * 128 + t;
  float acc = 0.f;
  for (int d = 0; d < D_; ++d) acc = fmaf(xs[d], Wq[(long)d * D_ + n], acc);
  q[b * D_ + n] = acc + bq[n];
}

// qt[b,h,l] = sum_d q[b,h*128+d] * Wk_up[l,h*128+d];  blog[b,h] = q_h . bk_up_h
__global__ __launch_bounds__(256) void qt_kernel(
    const float* __restrict__ q, const float* __restrict__ Wkvu,
    const float* __restrict__ bkvu, float* __restrict__ qt,
    float* __restrict__ blog) {
  __shared__ float qh[DH_];
  __shared__ float red[DH_];
  const int h = blockIdx.x, b = blockIdx.y, t = threadIdx.x;
  if (t < DH_) qh[t] = q[b * D_ + h * DH_ + t];
  __syncthreads();
  for (int l = t; l < L_; l += 256) {
    const float* wr = Wkvu + (long)l * 4096 + h * DH_;
    float acc = 0.f;
    for (int d = 0; d < DH_; d += 4) {
      float4 w4 = *(const float4*)(wr + d);
      acc = fmaf(qh[d], w4.x, acc);
      acc = fmaf(qh[d + 1], w4.y, acc);
      acc = fmaf(qh[d + 2], w4.z, acc);
      acc = fmaf(qh[d + 3], w4.w, acc);
    }
    qt[((long)b * H_ + h) * L_ + l] = acc;
  }
  if (t < DH_) red[t] = qh[t] * bkvu[h * DH_ + t];
  __syncthreads();
  if (t == 0) {
    float s = 0.f;
    for (int i = 0; i < DH_; ++i) s += red[i];
    blog[b * H_ + h] = s;
  }
}

// logits[b,h,k] over SLOTS entries via rowmapExt  (f32)
__global__ __launch_bounds__(256) void logits_kernel(
    const float* __restrict__ Kd, const int* __restrict__ rowmapExt,
    const float* __restrict__ qt, const float* __restrict__ blog,
    float* __restrict__ logits) {
  const int b = blockIdx.y;
  const int k = blockIdx.x * 16 + (threadIdx.x >> 4);
  const int h = threadIdx.x & 15;
  const float* kr = Kd + (long)rowmapExt[b * SLOTS + k] * L_;
  const float* qr = qt + ((long)b * H_ + h) * L_;
  float acc = 0.f;
  for (int l = 0; l < L_; l += 4) {
    float4 kv = *(const float4*)(kr + l);
    acc = fmaf(qr[l], kv.x, acc);
    acc = fmaf(qr[l + 1], kv.y, acc);
    acc = fmaf(qr[l + 2], kv.z, acc);
    acc = fmaf(qr[l + 3], kv.w, acc);
  }
  logits[((long)b * H_ + h) * SLOTS + k] =
      (acc + blog[b * H_ + h]) * 0.088388347648318447f;
}

// softmax over SLOTS with per-slot multipliers (hedged rows 0.5, pads 0)
__global__ __launch_bounds__(256) void softmax_kernel(
    float* __restrict__ logits, const float* __restrict__ multExt) {
  __shared__ double red[256];
  __shared__ float redf[256];
  const int bh = blockIdx.x;
  const int b = bh >> 4;
  float* row = logits + (long)bh * SLOTS;
  const float* mult = multExt + b * SLOTS;
  const int t = threadIdx.x;
  float m = -3.4e38f;
  for (int i = t; i < SLOTS; i += 256) m = fmaxf(m, row[i]);
  redf[t] = m; __syncthreads();
  for (int off = 128; off > 0; off >>= 1) {
    if (t < off) redf[t] = fmaxf(redf[t], redf[t + off]);
    __syncthreads();
  }
  m = redf[0]; __syncthreads();
  double s = 0.0;
  for (int i = t; i < SLOTS; i += 256)
    s += (double)mult[i] * exp((double)(row[i] - m));
  red[t] = s; __syncthreads();
  for (int off = 128; off > 0; off >>= 1) {
    if (t < off) red[t] += red[t + off];
    __syncthreads();
  }
  const double inv = 1.0 / red[0];
  __syncthreads();
  for (int i = t; i < SLOTS; i += 256)
    row[i] = (float)((double)mult[i] * exp((double)(row[i] - m)) * inv);
}

// vt[b,h,l] = sum_k attn[b,h,k] * Vsel[b,k,l]  over SLOTS (f32)
__global__ __launch_bounds__(256) void vt_kernel(
    const float* __restrict__ Vsel, const float* __restrict__ attn,
    float* __restrict__ vt) {
  const int b = blockIdx.y;
  const int l = blockIdx.x * 64 + (threadIdx.x & 63);
  const int hg = threadIdx.x >> 6;
  float acc[4] = {0.f, 0.f, 0.f, 0.f};
  const float* ar = attn + (long)b * H_ * SLOTS;
#pragma unroll 4
  for (int k = 0; k < SLOTS; ++k) {
    float v = Vsel[((long)b * SLOTS + k) * L_ + l];
#pragma unroll
    for (int a = 0; a < 4; ++a)
      acc[a] = fmaf(ar[(hg * 4 + a) * SLOTS + k], v, acc[a]);
  }
#pragma unroll
  for (int a = 0; a < 4; ++a)
    vt[((long)b * H_ + hg * 4 + a) * L_ + l] = acc[a];
}

// o[b,h*128+d] = vt[b,h,:] . Wv_up[:,h*128+d] + bv_up[h*128+d]  (f32)
__global__ __launch_bounds__(128) void oproj_kernel(
    const float* __restrict__ vt, const float* __restrict__ Wkvu,
    const float* __restrict__ bkvu, float* __restrict__ o) {
  __shared__ float vs[L_];
  const int h = blockIdx.x, b = blockIdx.y, t = threadIdx.x;
  for (int i = t; i < L_ / 4; i += 128)
    ((float4*)vs)[i] = ((const float4*)(vt + ((long)b * H_ + h) * L_))[i];
  __syncthreads();
  const int col = h * DH_ + t;
  float acc = 0.f;
  for (int l = 0; l < L_; ++l)
    acc = fmaf(vs[l], Wkvu[(long)l * 4096 + 2048 + col], acc);
  o[b * D_ + col] = acc + bkvu[2048 + col];
}

// out[b,n] = o[b,:] @ Wout[:,n] + bout[n]  (f32)
__global__ __launch_bounds__(128) void out_kernel(
    const float* __restrict__ o, const float* __restrict__ Wout,
    const float* __restrict__ bout, float* __restrict__ out) {
  __shared__ float os[D_];
  const int b = blockIdx.y, t = threadIdx.x;
  for (int i = t; i < D_ / 4; i += 128)
    ((float4*)os)[i] = ((const float4*)(o + (long)b * D_))[i];
  __syncthreads();
  const int n = blockIdx.x * 128 + t;
  float acc = 0.f;
  for (int d = 0; d < D_; ++d) acc = fmaf(os[d], Wout[(long)d * D_ + n], acc);
  out[b * D_ + n] = acc + bout[n];
}

extern "C" void kernel_launch(void* const* d_in, const int* in_sizes, int n_in,
                              void* d_out, int out_size, void* d_ws, size_t ws_size,
                              hipStream_t stream) {
  const float* x    = (const float*)d_in[0];
  const float* Wq   = (const float*)d_in[1];
  const float* bq   = (const float*)d_in[2];
  const float* Wkvd = (const float*)d_in[3];
  const float* bkvd = (const float*)d_in[4];
  const float* Wqd  = (const float*)d_in[5];
  const float* bqd  = (const float*)d_in[6];
  const float* Wkvu = (const float*)d_in[7];
  const float* bkvu = (const float*)d_in[8];
  const float* Wo   = (const float*)d_in[9];
  const float* bo   = (const float*)d_in[10];
  float* out = (float*)d_out;

  char* p = (char*)d_ws;
  auto alloc = [&](size_t bytes) {
    char* r = p;
    p += (bytes + 255) & ~(size_t)255;
    return r;
  };
  float*  Kd       = (float*)alloc((size_t)B_ * S_ * L_ * 4);       // 134.2 MB
  ushort* Kq8      = (ushort*)alloc((size_t)B_ * S_ * L_ * 2);      // 67.1 MB
  float*  Vsel     = (float*)alloc((size_t)B_ * SLOTS * L_ * 4);    // 34.6 MB
  ushort* Wsp      = (ushort*)alloc((size_t)3 * 64 * 4 * 1024 * 8 * 2);  // 12.6 MB
  ushort* Wq8      = (ushort*)alloc((size_t)D_ * L_ * 2);           // 2 MB
  double* qpart    = (double*)alloc((size_t)B_ * QCH * L_ * 8);     // 1 MB
  float*  scores   = (float*)alloc((size_t)B_ * S_ * 4);
  float*  qidx     = (float*)alloc((size_t)B_ * L_ * 4);
  int*    rowmap   = (int*)alloc((size_t)B_ * TOPK_ * 4);
  int*    rowmapE  = (int*)alloc((size_t)B_ * SLOTS * 4);
  float*  multE    = (float*)alloc((size_t)B_ * SLOTS * 4);
  float*  vstarF   = (float*)alloc((size_t)B_ * 4);
  int2*   riskyL   = (int2*)alloc((size_t)RCAP * 8);                // 1 MB
  int*    riskyCnt = (int*)alloc(256);
  int*    flagArr  = (int*)alloc((size_t)B_ * S_ * 4);              // 0.26 MB
  int*    extraR   = (int*)alloc((size_t)B_ * EXTCAP * 4);
  int*    extraCnt = (int*)alloc((size_t)B_ * 4);
  int*    cntI2O   = (int*)alloc((size_t)B_ * 4);
  float*  qv       = (float*)alloc((size_t)B_ * D_ * 4);
  float*  qt       = (float*)alloc((size_t)B_ * H_ * L_ * 4);
  float*  blog     = (float*)alloc((size_t)B_ * H_ * 4);
  float*  logits   = (float*)alloc((size_t)B_ * H_ * SLOTS * 4);
  float*  vt       = (float*)alloc((size_t)B_ * H_ * L_ * 4);
  float*  ov       = (float*)alloc((size_t)B_ * D_ * 4);
  (void)ws_size; (void)in_sizes; (void)n_in; (void)out_size;

  zero_kernel<<<(B_ * S_ + 255) / 256, 256, 0, stream>>>(flagArr, riskyCnt, extraCnt, cntI2O);
  // one-shot weight preprocessing
  wsplit_kernel<<<dim3(4, 64), 256, 0, stream>>>(Wkvd, Wsp);
  wq8_kernel<<<(D_ * L_ / 4) / 256, 256, 0, stream>>>(Wqd, Wq8);
  // K_down via bf16-split MFMA, 2 half-grid dispatches (bit-identical math)
  gemm_mfma<true><<<dim3(4, 256), 256, 0, stream>>>(
      x, Wsp, 0, 0, bkvd, Kd, Kq8, nullptr, riskyL, riskyCnt);
  gemm_mfma<true><<<dim3(4, 256), 256, 0, stream>>>(
      x, Wsp, 0, 256, bkvd, Kd, Kq8, nullptr, riskyL, riskyCnt);
  // qidx: parallel partials + ordered f64 reduce
  qidx_part<<<dim3(QCH, B_), 256, 0, stream>>>(x, Wq8, qpart);
  qidx_reduce<<<(B_ * L_) / 256, 256, 0, stream>>>(qpart, bqd, qidx);
  scores_kernel<<<(B_ * S_) / 4, 256, 0, stream>>>(Kq8, qidx, scores);
  topk_kernel<<<B_, 256, 0, stream>>>(scores, rowmap, vstarF);
  // hedge: find disputed rows + counterparties, build extended rowmap/mults
  risky_eval<<<RCAP / 256, 256, 0, stream>>>(riskyL, riskyCnt, Kq8, qidx, scores, vstarF,
                                             flagArr, extraR, extraCnt, cntI2O);
  counterparty_kernel<<<B_, 256, 0, stream>>>(scores, rowmap, vstarF, flagArr, extraR, extraCnt, cntI2O);
  buildext_kernel<<<dim3((SLOTS + 255) / 256, B_), 256, 0, stream>>>(rowmap, extraR, extraCnt, flagArr, rowmapE, multE);
  // V_down at selected+hedged rows via MFMA (cols 512..1023 of Wkv_down)
  gemm_mfma<false><<<dim3(4, (B_ * SLOTS) / 128), 256, 0, stream>>>(
      x, Wsp, 512, 0, bkvd + 512, Vsel, nullptr, rowmapE, nullptr, nullptr);
  // attention (up-projections folded)
  qproj_kernel<<<dim3(D_ / 128, B_), 128, 0, stream>>>(x, Wq, bq, qv);
  qt_kernel<<<dim3(H_, B_), 256, 0, stream>>>(qv, Wkvu, bkvu, qt, blog);
  logits_kernel<<<dim3(SLOTS / 16, B_), 256, 0, stream>>>(Kd, rowmapE, qt, blog, logits);
  softmax_kernel<<<B_ * H_, 256, 0, stream>>>(logits, multE);
  vt_kernel<<<dim3(L_ / 64, B_), 256, 0, stream>>>(Vsel, logits, vt);
  oproj_kernel<<<dim3(H_, B_), 128, 0, stream>>>(vt, Wkvu, bkvu, ov);
  out_kernel<<<dim3(D_ / 128, B_), 128, 0, stream>>>(ov, Wo, bo, out);
}